// Round 13
// baseline (488.804 us; speedup 1.0000x reference)
//
#include <hip/hip_runtime.h>
#include <hip/hip_bf16.h>
#include <math.h>

// ---------------------------------------------------------------------------
// VQ quantizer:
//   in[0] = z        (16,256,32,32) fp32   -> N=16384 vectors of C=256
//   in[1] = codebook (8192,256)     fp32
//   out   = [ z_q (B,C,H,W) 4194304 | loss | ortho | perplexity | idx(16384) as float ]
//
// idx strategy (two-stage, bit-matching the R2..R12 passing semantics):
//   Stage A: bf16 MFMA GEMM; tilemin[t][n] = -2*max_j dot_approx (err<=1.54e-4)
//   Stage B: rows whose tilemin is within MARGIN of rowmin get the EXACT fp32
//            chain recomputed tile-centrically; d = fmaf(-2,acc, A_n + ce_j)
//            == R2 bits; packed-key atomicMin, lowest-index tie-break.
//
// R13 = R12 with k_mfma widened to 128n x 256j per block (one A tile, two
// B j-tiles; wave tile 64n x 128j) -> 64 MFMA per chunk per wave (2x), same
// gload_lds DMA + XOR swizzle, same kc/kk MFMA order -> tilemin bits ==.
// ---------------------------------------------------------------------------

#define N_E     8192
#define C_DIM   256
#define N_VEC   16384            // 16*32*32
#define N_ELEM  4194304          // 16*256*32*32
#define MARGIN  6.0e-4f

// ws layout (bytes) -- zero-init fields packed first (single memset)
#define WS_COUNTS   0            // int[8192]                 32768
#define WS_M        32768        // float[65536]              262144
#define WS_ACCUM    294912       // double[2]                 16
#define WS_LISTLEN  294928       // int[64]                   256
#define WS_ZERO_BYTES 295184
#define WS_CE       295184       // float[8192]               32768
#define WS_RN       327952       // float[8192]               32768
#define WS_A        360720       // float[16384]              65536
#define WS_KEYS     426256       // u64[16384]                131072
#define WS_LISTS    557328       // int[64*16384]             4194304
#define WS_TILEMIN  4751632      // float[64*16384] [t][n]    4194304
#define WS_ZBF      8945936      // ushort[16384*256]         8388608
#define WS_CBBF     17334544     // ushort[8192*256]          4194304
#define WS_THR      21528848     // float[16384]              65536
#define WS_ZT       21594384     // float[16384*256]          16777216

typedef short short8v __attribute__((ext_vector_type(8)));
typedef float f32x4  __attribute__((ext_vector_type(4)));

__device__ inline unsigned short f2bf(float f) {       // RNE fp32->bf16 (no NaN in data)
    unsigned int x = __float_as_uint(f);
    return (unsigned short)((x + 0x7fffu + ((x >> 16) & 1u)) >> 16);
}

// async 16B/lane global->LDS DMA (gfx950).  LDS dest = wave-uniform base +
// lane*16; global src is per-lane.
__device__ inline void gload16(const void* g, void* l) {
    __builtin_amdgcn_global_load_lds(
        (const __attribute__((address_space(1))) unsigned int*)g,
        (__attribute__((address_space(3))) unsigned int*)l, 16, 0, 0);
}

// ---------------------------------------------------------------------------
// codebook prep: row sqnorm ce (bits == R2..R12), recip norm rn, bf16 cast
__global__ __launch_bounds__(256) void k_cbprep(const float* __restrict__ cb,
                                                float* __restrict__ ce,
                                                float* __restrict__ rn,
                                                unsigned short* __restrict__ cbbf) {
    int j = blockIdx.x;
    int tid = threadIdx.x;
    float v = cb[(size_t)j * C_DIM + tid];
    cbbf[(size_t)j * C_DIM + tid] = f2bf(v);
    float s = v * v;
    #pragma unroll
    for (int off = 32; off > 0; off >>= 1) s += __shfl_down(s, off, 64);
    __shared__ float sh[4];
    if ((tid & 63) == 0) sh[tid >> 6] = s;
    __syncthreads();
    if (tid == 0) {
        float t = sh[0] + sh[1] + sh[2] + sh[3];
        ce[j] = t;
        rn[j] = 1.0f / sqrtf(t);
    }
}

// ---------------------------------------------------------------------------
// z prep: LDS-staged transpose -> zbf (bf16) + zT (fp32), both with coalesced
// 16B/lane writes; A[n] computed from the LDS tile with the R2-VERBATIM
// k-ascending fmaf chain (same values, same order -> identical bits).
__global__ __launch_bounds__(256) void k_ztrans(const float* __restrict__ z,
                                                unsigned short* __restrict__ zbf,
                                                float* __restrict__ zT,
                                                float* __restrict__ A) {
    __shared__ float tile[64 * 260];             // [hw][c], stride 260
    const int tid = threadIdx.x;
    const int n0 = blockIdx.x * 64;
    const int b = n0 >> 10, hw0 = n0 & 1023;
    const float* zp = z + (size_t)b * 262144 + hw0;

    const int hw = tid & 63, cg = tid >> 6;      // 4 c per pass, coalesced over hw
    #pragma unroll 8
    for (int p = 0; p < 64; ++p) {
        int c = p * 4 + cg;
        tile[hw * 260 + c] = zp[(size_t)c * 1024 + hw];
    }
    __syncthreads();

    if (tid < 64) {                              // A[n]: R2-verbatim chain
        float a = 0.0f;
        #pragma unroll 8
        for (int c = 0; c < C_DIM; ++c) {
            float v = tile[tid * 260 + c];
            a = fmaf(v, v, a);
        }
        A[n0 + tid] = a;
    }

    const int r = tid >> 2, q = tid & 3;         // row, 64-c quarter
    unsigned short* dst = zbf + (size_t)(n0 + r) * C_DIM + q * 64;
    float* dstT         = zT  + (size_t)(n0 + r) * C_DIM + q * 64;
    const float* src = &tile[r * 260 + q * 64];
    #pragma unroll
    for (int i = 0; i < 8; ++i) {
        f32x4 lo = *(const f32x4*)&src[i * 8];
        f32x4 hi = *(const f32x4*)&src[i * 8 + 4];
        *(f32x4*)&dstT[i * 8]     = lo;
        *(f32x4*)&dstT[i * 8 + 4] = hi;
        short8v u;
        #pragma unroll
        for (int x = 0; x < 4; ++x) { u[x] = (short)f2bf(lo[x]); u[4 + x] = (short)f2bf(hi[x]); }
        *(short8v*)(dst + i * 8) = u;            // 16B/lane, rows contiguous
    }
}

// ---------------------------------------------------------------------------
// Stage A: bf16 MFMA GEMM, 128n x 256j per block (4 waves; wave tile
// 64n x 128j = one tilemin tile per wave), K=256.  Staging via global_load_lds
// DMA into LINEAR tiles; XOR slot swizzle on BOTH global source and LDS read
// (R12-verbatim pattern, conflict-free).  2-level XCD swizzle: XCD x owns
// by in [16x,16x+16), sweeps 8-bx2 j-stripes (per-XCD set ~2MB < 4MB L2).
// MFMA kc/kk/acc order verbatim R7/R12 -> tilemin bits unchanged.
__global__ __launch_bounds__(256) void k_mfma(const unsigned short* __restrict__ zbf,
                                              const unsigned short* __restrict__ cbbf,
                                              float* __restrict__ tilemin) {
    __shared__ unsigned short As[128 * 64];   // [n][k] linear (DMA dest)
    __shared__ unsigned short Bs[256 * 64];   // [j][k] linear
    __shared__ float smin[2][128];            // [j-tile][row]

    const int tid = threadIdx.x;
    const int lin = blockIdx.x;                           // 0..4095
    const int x = lin & 7, r = lin >> 3;                  // XCD, rank within
    const int jp = r >> 7, q = r & 127;
    const int by = x * 16 + (q >> 3), bx2 = jp * 8 + (q & 7);
    const int n0 = by * 128, j0 = bx2 * 256;
    const int wave = tid >> 6, lane = tid & 63;
    const int wx = wave & 1, wy = wave >> 1;              // wave tile: 64n x 128j
    const int g = lane >> 4, c = lane & 15;

    // DMA staging: lane l -> row +(l>>3), LDS slot (l&7), global slot (l&7)^(l>>3)
    const int lrow  = lane >> 3;
    const int lslot = (lane & 7) ^ lrow;
    const int ra = wave * 32;                             // A rows per wave: 32
    const int rb = wave * 64;                             // B rows per wave: 64

    f32x4 acc[4][8];
    #pragma unroll
    for (int i = 0; i < 4; ++i)
        #pragma unroll
        for (int j = 0; j < 8; ++j) acc[i][j] = (f32x4){0.f, 0.f, 0.f, 0.f};

    for (int kc = 0; kc < C_DIM; kc += 64) {
        __syncthreads();                                  // prev reads done
        #pragma unroll
        for (int i = 0; i < 4; ++i) {
            const int row8 = ra + i * 8;
            gload16(zbf + (size_t)(n0 + row8 + lrow) * C_DIM + kc + lslot * 8,
                    &As[row8 * 64]);
        }
        #pragma unroll
        for (int i = 0; i < 8; ++i) {
            const int row8 = rb + i * 8;
            gload16(cbbf + (size_t)(j0 + row8 + lrow) * C_DIM + kc + lslot * 8,
                    &Bs[row8 * 64]);
        }
        __syncthreads();                                  // vmcnt(0): tiles resident

        #pragma unroll
        for (int kk = 0; kk < 2; ++kk) {
            const int sw = ((kk * 4 + g) ^ (c & 7)) * 8;
            short8v a[4], b[8];
            #pragma unroll
            for (int f = 0; f < 4; ++f)
                a[f] = *(const short8v*)&As[(wy * 64 + f * 16 + c) * 64 + sw];
            #pragma unroll
            for (int f = 0; f < 8; ++f)
                b[f] = *(const short8v*)&Bs[(wx * 128 + f * 16 + c) * 64 + sw];
            #pragma unroll
            for (int nf = 0; nf < 4; ++nf)
                #pragma unroll
                for (int jf = 0; jf < 8; ++jf)
                    acc[nf][jf] = __builtin_amdgcn_mfma_f32_16x16x32_bf16(
                        a[nf], b[jf], acc[nf][jf], 0, 0, 0);
        }
    }

    // C layout: col(j) = lane&15, row(n) = (lane>>4)*4 + reg.  max over the
    // wave's 128-j span (= one tilemin tile); single writer per row.
    #pragma unroll
    for (int nf = 0; nf < 4; ++nf) {
        #pragma unroll
        for (int rr = 0; rr < 4; ++rr) {
            float mx = acc[nf][0][rr];
            #pragma unroll
            for (int jf = 1; jf < 8; ++jf) mx = fmaxf(mx, acc[nf][jf][rr]);
            #pragma unroll
            for (int off = 1; off < 16; off <<= 1)
                mx = fmaxf(mx, __shfl_xor(mx, off, 64));
            if (c == 0) smin[wx][wy * 64 + nf * 16 + g * 4 + rr] = -2.0f * mx;
        }
    }
    __syncthreads();
    {
        const int tile = tid >> 7, row = tid & 127;       // 2 x 128
        tilemin[(size_t)(bx2 * 2 + tile) * N_VEC + n0 + row] = smin[tile][row];
    }
}

// ---------------------------------------------------------------------------
// Stage B1a: thr[n] = min_t tilemin[t][n] + MARGIN; also re-arms keys[n].
__global__ __launch_bounds__(256) void k_rowmin(const float* __restrict__ tilemin,
                                               float* __restrict__ thr,
                                               unsigned long long* __restrict__ keys) {
    __shared__ float red[4][64];
    const int nl = threadIdx.x & 63, tg = threadIdx.x >> 6;
    const int n = blockIdx.x * 64 + nl;
    float m = 3.4e38f;
    #pragma unroll
    for (int i = 0; i < 16; ++i)
        m = fminf(m, tilemin[(size_t)(tg * 16 + i) * N_VEC + n]);
    red[tg][nl] = m;
    __syncthreads();
    if (tg == 0) {
        thr[n] = fminf(fminf(red[0][nl], red[1][nl]),
                       fminf(red[2][nl], red[3][nl])) + MARGIN;
        keys[n] = ~0ull;
    }
}

// ---------------------------------------------------------------------------
// Stage B1b: build per-tile candidate lists (wave-aggregated compaction).
__global__ __launch_bounds__(256) void k_build(const float* __restrict__ tilemin,
                                               const float* __restrict__ thr,
                                               int* __restrict__ listlen,
                                               int* __restrict__ lists) {
    const int t = blockIdx.x;
    const int lane = threadIdx.x & 63;
    #pragma unroll
    for (int it = 0; it < 8; ++it) {
        int n = blockIdx.y * 2048 + it * 256 + threadIdx.x;
        bool qq = tilemin[(size_t)t * N_VEC + n] <= thr[n];
        unsigned long long mask = __ballot(qq);
        if (mask) {
            int ldr = __ffsll(mask) - 1;
            int base = 0;
            if (lane == ldr) base = atomicAdd(&listlen[t], __popcll(mask));
            base = __shfl(base, ldr, 64);
            if (qq) {
                int pre = __popcll(mask & ((1ull << lane) - 1ull));
                lists[t * N_VEC + base + pre] = n;
            }
        }
    }
}

// ---------------------------------------------------------------------------
// Stage B2: tile-centric exact refine (R7/R10 structure; z staged from zT with
// the R5-verbatim coalesced b128 pattern).  grid (64, 128).
__global__ __launch_bounds__(256) void k_refine2(const float* __restrict__ zT,
                                                 const float* __restrict__ cb,
                                                 const float* __restrict__ ce,
                                                 const float* __restrict__ A,
                                                 const int* __restrict__ listlen,
                                                 const int* __restrict__ lists,
                                                 unsigned long long* __restrict__ keys) {
    __shared__ float e_s[128 * 68];
    __shared__ float z_s[32 * 68];
    __shared__ int   rows_s[32];

    const int t = blockIdx.x;
    const int len = listlen[t];
    const int tid = threadIdx.x;
    const int jg = tid & 31, rg = tid >> 5;
    const int j0 = t * 128;

    for (int b0 = blockIdx.y * 32; b0 < len; b0 += 128 * 32) {
        const int nrows = min(32, len - b0);
        __syncthreads();                           // protect prev batch's LDS
        if (tid < 32)
            rows_s[tid] = lists[t * N_VEC + b0 + min(tid, nrows - 1)];  // pad dup row0

        float acc[4][4];
        #pragma unroll
        for (int rr = 0; rr < 4; ++rr)
            #pragma unroll
            for (int jj = 0; jj < 4; ++jj) acc[rr][jj] = 0.0f;

        for (int kc = 0; kc < C_DIM; kc += 64) {
            __syncthreads();
            {   // stage e chunk: 128 j x 64 k
                int jr = tid >> 1, ko = (tid & 1) * 32;
                #pragma unroll
                for (int i = 0; i < 8; ++i)
                    *(float4*)&e_s[jr * 68 + ko + i * 4] =
                        *(const float4*)&cb[(size_t)(j0 + jr) * C_DIM + kc + ko + i * 4];
            }
            {   // stage z chunk: 32 rows x 64 k from zT (R5-verbatim, coalesced)
                int r = tid >> 3, ko = (tid & 7) * 8;
                const float* zp = &zT[(size_t)rows_s[r] * C_DIM + kc + ko];
                *(float4*)&z_s[r * 68 + ko]     = *(const float4*)&zp[0];
                *(float4*)&z_s[r * 68 + ko + 4] = *(const float4*)&zp[4];
            }
            __syncthreads();

            #pragma unroll
            for (int k4 = 0; k4 < 16; ++k4) {
                float4 ef[4], zf[4];
                #pragma unroll
                for (int jj = 0; jj < 4; ++jj)
                    ef[jj] = *(const float4*)&e_s[(jg + 32 * jj) * 68 + k4 * 4];
                #pragma unroll
                for (int rr = 0; rr < 4; ++rr)
                    zf[rr] = *(const float4*)&z_s[(rg * 4 + rr) * 68 + k4 * 4];
                #pragma unroll
                for (int kk = 0; kk < 4; ++kk)       // k ascending: exact chain
                    #pragma unroll
                    for (int rr = 0; rr < 4; ++rr)
                        #pragma unroll
                        for (int jj = 0; jj < 4; ++jj)
                            acc[rr][jj] = fmaf(((const float*)&zf[rr])[kk],
                                               ((const float*)&ef[jj])[kk], acc[rr][jj]);
            }
        }

        // epilogue: exact d, packed key, min over jj then over jg lanes
        #pragma unroll
        for (int rr = 0; rr < 4; ++rr) {
            const int n = rows_s[rg * 4 + rr];
            const float An = A[n];
            unsigned long long best = ~0ull;
            #pragma unroll
            for (int jj = 0; jj < 4; ++jj) {
                int j = j0 + jg + 32 * jj;
                float tt = An + ce[j];
                float d = fmaf(-2.0f, acc[rr][jj], tt);   // == R2 epilogue bits
                unsigned int sd = __float_as_uint(d);
                sd = (sd & 0x80000000u) ? ~sd : (sd | 0x80000000u);
                unsigned long long key = ((unsigned long long)sd << 32) | (unsigned)j;
                best = key < best ? key : best;
            }
            #pragma unroll
            for (int off = 16; off > 0; off >>= 1) {      // reduce 32 jg lanes
                unsigned long long o = __shfl_xor(best, off, 64);
                best = o < best ? o : best;
            }
            if (jg == 0) atomicMin(&keys[n], best);
        }
    }
}

// ---------------------------------------------------------------------------
// gather z_q + idx unpack + histogram + fp64 SSE reduction
__global__ __launch_bounds__(256) void k_gather(const float* __restrict__ z,
                                                const float* __restrict__ cb,
                                                const unsigned long long* __restrict__ keys,
                                                float* __restrict__ out,
                                                float* __restrict__ out_idx,
                                                int* __restrict__ counts,
                                                double* __restrict__ sse) {
    int bh = blockIdx.x;                 // b*32 + h
    int b = bh >> 5, h = bh & 31;
    int tid = threadIdx.x;
    __shared__ int sidx[32];
    if (tid < 32) {
        int n = b * 1024 + h * 32 + tid;
        unsigned long long k = keys[n];
        int idx = (int)(k & 0xFFFFFFFFull);
        sidx[tid] = idx;
        out_idx[n] = (float)idx;
        atomicAdd(&counts[idx], 1);
    }
    __syncthreads();
    int w = tid & 31, cy = tid >> 5;
    int jid = sidx[w];
    const float* cbr = cb + (size_t)jid * C_DIM;
    size_t zb = (size_t)b * 262144 + h * 32 + w;

    double acc = 0.0;
    #pragma unroll 4
    for (int cc = 0; cc < 32; ++cc) {
        int c = cc * 8 + cy;
        float e = cbr[c];
        size_t zi = zb + (size_t)c * 1024;
        float d = e - z[zi];
        out[zi] = e;
        acc += (double)(d * d);
    }
    #pragma unroll
    for (int off = 32; off > 0; off >>= 1) acc += __shfl_down(acc, off, 64);
    __shared__ double sh[4];
    if ((tid & 63) == 0) sh[tid >> 6] = acc;
    __syncthreads();
    if (tid == 0) atomicAdd(sse, sh[0] + sh[1] + sh[2] + sh[3]);
}

// ---------------------------------------------------------------------------
// Gram matrix M = Wn^T Wn  (256x256), j-split with float atomics
__global__ __launch_bounds__(256) void k_gram(const float* __restrict__ cb,
                                              const float* __restrict__ rn,
                                              float* __restrict__ M) {
    __shared__ float aT[64][68];
    __shared__ float bT[64][68];
    int k0 = blockIdx.x * 64, l0 = blockIdx.y * 64;
    int jc0 = blockIdx.z * 256;
    int tid = threadIdx.x;
    int tk = tid & 15, tl = tid >> 4;
    float acc[4][4];
    #pragma unroll
    for (int i = 0; i < 4; ++i)
        #pragma unroll
        for (int l = 0; l < 4; ++l) acc[i][l] = 0.0f;

    for (int jc = jc0; jc < jc0 + 256; jc += 64) {
        __syncthreads();
        {
            int kk = tid & 63, jj0 = tid >> 6;
            #pragma unroll
            for (int p = 0; p < 16; ++p) {
                int jj = p * 4 + jj0;
                float r = rn[jc + jj];
                const float* row = cb + (size_t)(jc + jj) * C_DIM;
                aT[jj][kk] = row[k0 + kk] * r;
                bT[jj][kk] = row[l0 + kk] * r;
            }
        }
        __syncthreads();
        #pragma unroll 8
        for (int jj = 0; jj < 64; ++jj) {
            float4 av = *(const float4*)&aT[jj][tk * 4];
            float4 bv = *(const float4*)&bT[jj][tl * 4];
            float a4[4] = {av.x, av.y, av.z, av.w};
            float b4[4] = {bv.x, bv.y, bv.z, bv.w};
            #pragma unroll
            for (int i = 0; i < 4; ++i)
                #pragma unroll
                for (int l = 0; l < 4; ++l)
                    acc[i][l] = fmaf(a4[i], b4[l], acc[i][l]);
        }
    }
    #pragma unroll
    for (int i = 0; i < 4; ++i)
        #pragma unroll
        for (int l = 0; l < 4; ++l)
            atomicAdd(&M[(size_t)(k0 + tk * 4 + i) * C_DIM + l0 + tl * 4 + l], acc[i][l]);
}

// ---------------------------------------------------------------------------
// finalize scalars: loss, ortho = (||M||_F^2 - n_e)/n_e^2, perplexity
__global__ __launch_bounds__(256) void k_final(const float* __restrict__ M,
                                               const int* __restrict__ counts,
                                               const double* __restrict__ accum,
                                               float* __restrict__ out_scalars) {
    int tid = threadIdx.x;
    __shared__ double sh[4];

    double s = 0.0;
    for (int i = tid; i < C_DIM * C_DIM; i += 256) {
        double m = M[i];
        s += m * m;
    }
    #pragma unroll
    for (int off = 32; off > 0; off >>= 1) s += __shfl_down(s, off, 64);
    if ((tid & 63) == 0) sh[tid >> 6] = s;
    __syncthreads();
    double S = sh[0] + sh[1] + sh[2] + sh[3];
    __syncthreads();

    double H = 0.0;
    for (int j = tid; j < N_E; j += 256) {
        double p = counts[j] * (1.0 / (double)N_VEC);
        H += p * log(p + 1e-10);
    }
    #pragma unroll
    for (int off = 32; off > 0; off >>= 1) H += __shfl_down(H, off, 64);
    if ((tid & 63) == 0) sh[tid >> 6] = H;
    __syncthreads();

    if (tid == 0) {
        double Hs = sh[0] + sh[1] + sh[2] + sh[3];
        out_scalars[0] = (float)(1.25 * accum[0] / (double)N_ELEM);        // loss
        out_scalars[1] = (float)((S - (double)N_E) / ((double)N_E * N_E)); // ortho
        out_scalars[2] = (float)exp(-Hs);                                  // perplexity
    }
}

// ---------------------------------------------------------------------------
extern "C" void kernel_launch(void* const* d_in, const int* in_sizes, int n_in,
                              void* d_out, int out_size, void* d_ws, size_t ws_size,
                              hipStream_t stream) {
    (void)in_sizes; (void)n_in; (void)out_size; (void)ws_size;
    const float* z  = (const float*)d_in[0];
    const float* cb = (const float*)d_in[1];
    float* out = (float*)d_out;

    char* ws = (char*)d_ws;
    int* counts            = (int*)(ws + WS_COUNTS);
    float* M               = (float*)(ws + WS_M);
    double* accum          = (double*)(ws + WS_ACCUM);
    int* listlen           = (int*)(ws + WS_LISTLEN);
    float* ce              = (float*)(ws + WS_CE);
    float* rn              = (float*)(ws + WS_RN);
    float* A               = (float*)(ws + WS_A);
    unsigned long long* keys = (unsigned long long*)(ws + WS_KEYS);
    int* lists             = (int*)(ws + WS_LISTS);
    float* tilemin         = (float*)(ws + WS_TILEMIN);
    unsigned short* zbf    = (unsigned short*)(ws + WS_ZBF);
    unsigned short* cbbf   = (unsigned short*)(ws + WS_CBBF);
    float* thr             = (float*)(ws + WS_THR);
    float* zT              = (float*)(ws + WS_ZT);

    float* out_scalars = out + N_ELEM;       // loss, ortho, perplexity
    float* out_idx     = out + N_ELEM + 3;   // 16384 idx as float

    hipMemsetAsync(ws, 0, WS_ZERO_BYTES, stream);   // counts + M + accum + listlen

    k_cbprep<<<N_E, 256, 0, stream>>>(cb, ce, rn, cbbf);
    k_ztrans<<<N_VEC / 64, 256, 0, stream>>>(z, zbf, zT, A);
    k_mfma<<<4096, 256, 0, stream>>>(zbf, cbbf, tilemin);
    k_rowmin<<<N_VEC / 64, 256, 0, stream>>>(tilemin, thr, keys);
    k_build<<<dim3(64, 8), 256, 0, stream>>>(tilemin, thr, listlen, lists);
    k_refine2<<<dim3(64, 128), 256, 0, stream>>>(zT, cb, ce, A, listlen, lists, keys);
    k_gather<<<512, 256, 0, stream>>>(z, cb, keys, out, out_idx, counts, accum);
    k_gram<<<dim3(4, 4, 32), 256, 0, stream>>>(cb, rn, M);
    k_final<<<1, 256, 0, stream>>>(M, counts, accum, out_scalars);
}

// Round 14
// 359.174 us; speedup vs baseline: 1.3609x; 1.3609x over previous
//
#include <hip/hip_runtime.h>
#include <hip/hip_bf16.h>
#include <math.h>

// ---------------------------------------------------------------------------
// VQ quantizer:
//   in[0] = z        (16,256,32,32) fp32   -> N=16384 vectors of C=256
//   in[1] = codebook (8192,256)     fp32
//   out   = [ z_q (B,C,H,W) 4194304 | loss | ortho | perplexity | idx(16384) as float ]
//
// idx strategy (two-stage, bit-matching the R2..R12 passing semantics):
//   Stage A: bf16 MFMA GEMM; tilemin[t][n] = -2*max_j dot_approx (err<=1.54e-4)
//   Stage B: rows whose tilemin is within MARGIN of rowmin get the EXACT fp32
//            chain recomputed tile-centrically; d = fmaf(-2,acc, A_n + ce_j)
//            == R2 bits; packed-key atomicMin, lowest-index tie-break.
//
// R14 = R12 green build (k_mfma reverted verbatim: 128n x 128j, gload_lds DMA
// + XOR swizzle, 0 bank conflicts) with:
//   (a) k_gram fused into the k_mfma dispatch (blocks 8192..8703, LDS overlay,
//       block-uniform branch; both bodies verbatim) -> gram overlaps mfma tail;
//   (b) k_final's 65K-element M-reduction + 8K-entropy parallelized into k_msq
//       (96 blocks, fp64 atomics); k_final is now 3 scalar ops.
// ---------------------------------------------------------------------------

#define N_E     8192
#define C_DIM   256
#define N_VEC   16384            // 16*32*32
#define N_ELEM  4194304          // 16*256*32*32
#define MARGIN  6.0e-4f

// ws layout (bytes) -- zero-init fields packed first (single memset)
#define WS_COUNTS   0            // int[8192]                 32768
#define WS_M        32768        // float[65536]              262144
#define WS_ACCUM    294912       // double[4] {sse,S,H,-}     32
#define WS_LISTLEN  294944       // int[64]                   256
#define WS_ZERO_BYTES 295200
#define WS_CE       295200       // float[8192]               32768
#define WS_RN       327968       // float[8192]               32768
#define WS_A        360736       // float[16384]              65536
#define WS_KEYS     426272       // u64[16384]                131072
#define WS_LISTS    557344       // int[64*16384]             4194304
#define WS_TILEMIN  4751648      // float[64*16384] [t][n]    4194304
#define WS_ZBF      8945952      // ushort[16384*256]         8388608
#define WS_CBBF     17334560     // ushort[8192*256]          4194304
#define WS_THR      21528864     // float[16384]              65536
#define WS_ZT       21594400     // float[16384*256]          16777216

typedef short short8v __attribute__((ext_vector_type(8)));
typedef float f32x4  __attribute__((ext_vector_type(4)));

__device__ inline unsigned short f2bf(float f) {       // RNE fp32->bf16 (no NaN in data)
    unsigned int x = __float_as_uint(f);
    return (unsigned short)((x + 0x7fffu + ((x >> 16) & 1u)) >> 16);
}

// async 16B/lane global->LDS DMA (gfx950).  LDS dest = wave-uniform base +
// lane*16; global src is per-lane.
__device__ inline void gload16(const void* g, void* l) {
    __builtin_amdgcn_global_load_lds(
        (const __attribute__((address_space(1))) unsigned int*)g,
        (__attribute__((address_space(3))) unsigned int*)l, 16, 0, 0);
}

// ---------------------------------------------------------------------------
// codebook prep: row sqnorm ce (bits == R2..R12), recip norm rn, bf16 cast
__global__ __launch_bounds__(256) void k_cbprep(const float* __restrict__ cb,
                                                float* __restrict__ ce,
                                                float* __restrict__ rn,
                                                unsigned short* __restrict__ cbbf) {
    int j = blockIdx.x;
    int tid = threadIdx.x;
    float v = cb[(size_t)j * C_DIM + tid];
    cbbf[(size_t)j * C_DIM + tid] = f2bf(v);
    float s = v * v;
    #pragma unroll
    for (int off = 32; off > 0; off >>= 1) s += __shfl_down(s, off, 64);
    __shared__ float sh[4];
    if ((tid & 63) == 0) sh[tid >> 6] = s;
    __syncthreads();
    if (tid == 0) {
        float t = sh[0] + sh[1] + sh[2] + sh[3];
        ce[j] = t;
        rn[j] = 1.0f / sqrtf(t);
    }
}

// ---------------------------------------------------------------------------
// z prep: LDS-staged transpose -> zbf (bf16) + zT (fp32), both with coalesced
// 16B/lane writes; A[n] computed from the LDS tile with the R2-VERBATIM
// k-ascending fmaf chain (same values, same order -> identical bits).
__global__ __launch_bounds__(256) void k_ztrans(const float* __restrict__ z,
                                                unsigned short* __restrict__ zbf,
                                                float* __restrict__ zT,
                                                float* __restrict__ A) {
    __shared__ float tile[64 * 260];             // [hw][c], stride 260
    const int tid = threadIdx.x;
    const int n0 = blockIdx.x * 64;
    const int b = n0 >> 10, hw0 = n0 & 1023;
    const float* zp = z + (size_t)b * 262144 + hw0;

    const int hw = tid & 63, cg = tid >> 6;      // 4 c per pass, coalesced over hw
    #pragma unroll 8
    for (int p = 0; p < 64; ++p) {
        int c = p * 4 + cg;
        tile[hw * 260 + c] = zp[(size_t)c * 1024 + hw];
    }
    __syncthreads();

    if (tid < 64) {                              // A[n]: R2-verbatim chain
        float a = 0.0f;
        #pragma unroll 8
        for (int c = 0; c < C_DIM; ++c) {
            float v = tile[tid * 260 + c];
            a = fmaf(v, v, a);
        }
        A[n0 + tid] = a;
    }

    const int r = tid >> 2, q = tid & 3;         // row, 64-c quarter
    unsigned short* dst = zbf + (size_t)(n0 + r) * C_DIM + q * 64;
    float* dstT         = zT  + (size_t)(n0 + r) * C_DIM + q * 64;
    const float* src = &tile[r * 260 + q * 64];
    #pragma unroll
    for (int i = 0; i < 8; ++i) {
        f32x4 lo = *(const f32x4*)&src[i * 8];
        f32x4 hi = *(const f32x4*)&src[i * 8 + 4];
        *(f32x4*)&dstT[i * 8]     = lo;
        *(f32x4*)&dstT[i * 8 + 4] = hi;
        short8v u;
        #pragma unroll
        for (int x = 0; x < 4; ++x) { u[x] = (short)f2bf(lo[x]); u[4 + x] = (short)f2bf(hi[x]); }
        *(short8v*)(dst + i * 8) = u;            // 16B/lane, rows contiguous
    }
}

// ---------------------------------------------------------------------------
// Stage A + ortho Gram, one dispatch (8704 blocks):
//   blocks [0,8192):   R12-VERBATIM bf16 MFMA GEMM, 128n x 128j, gload_lds DMA
//                      into linear tiles, XOR slot swizzle on source AND read
//                      (conflict-free), 2-level XCD swizzle.  kc/kk/acc order
//                      verbatim -> tilemin bits unchanged.
//   blocks [8192,8704): k_gram body verbatim (M = Wn^T Wn, j-split atomics).
// LDS: one raw buffer overlaid by both paths (block-uniform branch).
__global__ __launch_bounds__(256) void k_mfma(const unsigned short* __restrict__ zbf,
                                              const unsigned short* __restrict__ cbbf,
                                              const float* __restrict__ cb,
                                              const float* __restrict__ rn,
                                              float* __restrict__ tilemin,
                                              float* __restrict__ M) {
    __shared__ unsigned long long ldsraw[4352];   // 34816 B, max(33.8K, 34.8K... capped)
    const int tid = threadIdx.x;

    if (blockIdx.x < 8192) {
        unsigned short* As = (unsigned short*)ldsraw;          // [128][64] linear
        unsigned short* Bs = As + 128 * 64;                    // [128][64] linear
        float (*smin)[2]   = (float(*)[2])(Bs + 128 * 64);     // [128][2]

        const int lin = blockIdx.x;
        const int x = lin & 7, r = lin >> 3;                   // XCD, rank within
        const int jp = r >> 7, q = r & 127;
        const int by = x * 16 + (q >> 3), bx = jp * 8 + (q & 7);
        const int n0 = by * 128, j0 = bx * 128;
        const int wave = tid >> 6, lane = tid & 63;
        const int wx = wave & 1, wy = wave >> 1;               // wave tile: 64n x 64j
        const int g = lane >> 4, c = lane & 15;

        const int lrow  = lane >> 3;
        const int lslot = (lane & 7) ^ lrow;
        const int rbase = wave * 32;                           // wave-uniform

        f32x4 acc[4][4];
        #pragma unroll
        for (int i = 0; i < 4; ++i)
            #pragma unroll
            for (int j = 0; j < 4; ++j) acc[i][j] = (f32x4){0.f, 0.f, 0.f, 0.f};

        for (int kc = 0; kc < C_DIM; kc += 64) {
            __syncthreads();                                   // prev reads done
            #pragma unroll
            for (int i = 0; i < 4; ++i) {
                const int row8 = rbase + i * 8;
                const unsigned short* ga =
                    zbf  + (size_t)(n0 + row8 + lrow) * C_DIM + kc + lslot * 8;
                const unsigned short* gb =
                    cbbf + (size_t)(j0 + row8 + lrow) * C_DIM + kc + lslot * 8;
                gload16(ga, &As[row8 * 64]);
                gload16(gb, &Bs[row8 * 64]);
            }
            __syncthreads();                                   // vmcnt(0): resident

            #pragma unroll
            for (int kk = 0; kk < 2; ++kk) {
                short8v a[4], b[4];
                #pragma unroll
                for (int f = 0; f < 4; ++f) {
                    const int row = wy * 64 + f * 16 + c;
                    a[f] = *(const short8v*)&As[row * 64 + (((kk * 4 + g) ^ (c & 7)) * 8)];
                }
                #pragma unroll
                for (int f = 0; f < 4; ++f) {
                    const int row = wx * 64 + f * 16 + c;
                    b[f] = *(const short8v*)&Bs[row * 64 + (((kk * 4 + g) ^ (c & 7)) * 8)];
                }
                #pragma unroll
                for (int nf = 0; nf < 4; ++nf)
                    #pragma unroll
                    for (int jf = 0; jf < 4; ++jf)
                        acc[nf][jf] = __builtin_amdgcn_mfma_f32_16x16x32_bf16(
                            a[nf], b[jf], acc[nf][jf], 0, 0, 0);
            }
        }

        // C layout: col(j) = lane&15, row(n) = (lane>>4)*4 + reg.  max over j.
        #pragma unroll
        for (int nf = 0; nf < 4; ++nf) {
            #pragma unroll
            for (int rr = 0; rr < 4; ++rr) {
                float mx = acc[nf][0][rr];
                #pragma unroll
                for (int jf = 1; jf < 4; ++jf) mx = fmaxf(mx, acc[nf][jf][rr]);
                #pragma unroll
                for (int off = 1; off < 16; off <<= 1)
                    mx = fmaxf(mx, __shfl_xor(mx, off, 64));
                if (c == 0) smin[wy * 64 + nf * 16 + g * 4 + rr][wx] = -2.0f * mx;
            }
        }
        __syncthreads();
        if (tid < 128)
            tilemin[(size_t)bx * N_VEC + n0 + tid] = fminf(smin[tid][0], smin[tid][1]);

    } else {
        // ---- gram path (verbatim body, linear block mapping) ----
        float* aT = (float*)ldsraw;               // [64][68]
        float* bT = aT + 64 * 68;                 // [64][68]
        const int gidx = blockIdx.x - 8192;       // 0..511
        const int k0 = (gidx & 3) * 64, l0 = ((gidx >> 2) & 3) * 64;
        const int jc0 = (gidx >> 4) * 256;
        const int tk = tid & 15, tl = tid >> 4;
        float acc[4][4];
        #pragma unroll
        for (int i = 0; i < 4; ++i)
            #pragma unroll
            for (int l = 0; l < 4; ++l) acc[i][l] = 0.0f;

        for (int jc = jc0; jc < jc0 + 256; jc += 64) {
            __syncthreads();
            {
                int kk = tid & 63, jj0 = tid >> 6;
                #pragma unroll
                for (int p = 0; p < 16; ++p) {
                    int jj = p * 4 + jj0;
                    float rr = rn[jc + jj];
                    const float* row = cb + (size_t)(jc + jj) * C_DIM;
                    aT[jj * 68 + kk] = row[k0 + kk] * rr;
                    bT[jj * 68 + kk] = row[l0 + kk] * rr;
                }
            }
            __syncthreads();
            #pragma unroll 8
            for (int jj = 0; jj < 64; ++jj) {
                float4 av = *(const float4*)&aT[jj * 68 + tk * 4];
                float4 bv = *(const float4*)&bT[jj * 68 + tl * 4];
                float a4[4] = {av.x, av.y, av.z, av.w};
                float b4[4] = {bv.x, bv.y, bv.z, bv.w};
                #pragma unroll
                for (int i = 0; i < 4; ++i)
                    #pragma unroll
                    for (int l = 0; l < 4; ++l)
                        acc[i][l] = fmaf(a4[i], b4[l], acc[i][l]);
            }
        }
        #pragma unroll
        for (int i = 0; i < 4; ++i)
            #pragma unroll
            for (int l = 0; l < 4; ++l)
                atomicAdd(&M[(size_t)(k0 + tk * 4 + i) * C_DIM + l0 + tl * 4 + l], acc[i][l]);
    }
}

// ---------------------------------------------------------------------------
// Stage B1a: thr[n] = min_t tilemin[t][n] + MARGIN; also re-arms keys[n].
__global__ __launch_bounds__(256) void k_rowmin(const float* __restrict__ tilemin,
                                               float* __restrict__ thr,
                                               unsigned long long* __restrict__ keys) {
    __shared__ float red[4][64];
    const int nl = threadIdx.x & 63, tg = threadIdx.x >> 6;
    const int n = blockIdx.x * 64 + nl;
    float m = 3.4e38f;
    #pragma unroll
    for (int i = 0; i < 16; ++i)
        m = fminf(m, tilemin[(size_t)(tg * 16 + i) * N_VEC + n]);
    red[tg][nl] = m;
    __syncthreads();
    if (tg == 0) {
        thr[n] = fminf(fminf(red[0][nl], red[1][nl]),
                       fminf(red[2][nl], red[3][nl])) + MARGIN;
        keys[n] = ~0ull;
    }
}

// ---------------------------------------------------------------------------
// Stage B1b: build per-tile candidate lists (wave-aggregated compaction).
__global__ __launch_bounds__(256) void k_build(const float* __restrict__ tilemin,
                                               const float* __restrict__ thr,
                                               int* __restrict__ listlen,
                                               int* __restrict__ lists) {
    const int t = blockIdx.x;
    const int lane = threadIdx.x & 63;
    #pragma unroll
    for (int it = 0; it < 8; ++it) {
        int n = blockIdx.y * 2048 + it * 256 + threadIdx.x;
        bool qq = tilemin[(size_t)t * N_VEC + n] <= thr[n];
        unsigned long long mask = __ballot(qq);
        if (mask) {
            int ldr = __ffsll(mask) - 1;
            int base = 0;
            if (lane == ldr) base = atomicAdd(&listlen[t], __popcll(mask));
            base = __shfl(base, ldr, 64);
            if (qq) {
                int pre = __popcll(mask & ((1ull << lane) - 1ull));
                lists[t * N_VEC + base + pre] = n;
            }
        }
    }
}

// ---------------------------------------------------------------------------
// Stage B2: tile-centric exact refine (R7/R10 structure; z staged from zT with
// the R5-verbatim coalesced b128 pattern).  grid (64, 128).
__global__ __launch_bounds__(256) void k_refine2(const float* __restrict__ zT,
                                                 const float* __restrict__ cb,
                                                 const float* __restrict__ ce,
                                                 const float* __restrict__ A,
                                                 const int* __restrict__ listlen,
                                                 const int* __restrict__ lists,
                                                 unsigned long long* __restrict__ keys) {
    __shared__ float e_s[128 * 68];
    __shared__ float z_s[32 * 68];
    __shared__ int   rows_s[32];

    const int t = blockIdx.x;
    const int len = listlen[t];
    const int tid = threadIdx.x;
    const int jg = tid & 31, rg = tid >> 5;
    const int j0 = t * 128;

    for (int b0 = blockIdx.y * 32; b0 < len; b0 += 128 * 32) {
        const int nrows = min(32, len - b0);
        __syncthreads();                           // protect prev batch's LDS
        if (tid < 32)
            rows_s[tid] = lists[t * N_VEC + b0 + min(tid, nrows - 1)];  // pad dup row0

        float acc[4][4];
        #pragma unroll
        for (int rr = 0; rr < 4; ++rr)
            #pragma unroll
            for (int jj = 0; jj < 4; ++jj) acc[rr][jj] = 0.0f;

        for (int kc = 0; kc < C_DIM; kc += 64) {
            __syncthreads();
            {   // stage e chunk: 128 j x 64 k
                int jr = tid >> 1, ko = (tid & 1) * 32;
                #pragma unroll
                for (int i = 0; i < 8; ++i)
                    *(float4*)&e_s[jr * 68 + ko + i * 4] =
                        *(const float4*)&cb[(size_t)(j0 + jr) * C_DIM + kc + ko + i * 4];
            }
            {   // stage z chunk: 32 rows x 64 k from zT (R5-verbatim, coalesced)
                int r = tid >> 3, ko = (tid & 7) * 8;
                const float* zp = &zT[(size_t)rows_s[r] * C_DIM + kc + ko];
                *(float4*)&z_s[r * 68 + ko]     = *(const float4*)&zp[0];
                *(float4*)&z_s[r * 68 + ko + 4] = *(const float4*)&zp[4];
            }
            __syncthreads();

            #pragma unroll
            for (int k4 = 0; k4 < 16; ++k4) {
                float4 ef[4], zf[4];
                #pragma unroll
                for (int jj = 0; jj < 4; ++jj)
                    ef[jj] = *(const float4*)&e_s[(jg + 32 * jj) * 68 + k4 * 4];
                #pragma unroll
                for (int rr = 0; rr < 4; ++rr)
                    zf[rr] = *(const float4*)&z_s[(rg * 4 + rr) * 68 + k4 * 4];
                #pragma unroll
                for (int kk = 0; kk < 4; ++kk)       // k ascending: exact chain
                    #pragma unroll
                    for (int rr = 0; rr < 4; ++rr)
                        #pragma unroll
                        for (int jj = 0; jj < 4; ++jj)
                            acc[rr][jj] = fmaf(((const float*)&zf[rr])[kk],
                                               ((const float*)&ef[jj])[kk], acc[rr][jj]);
            }
        }

        // epilogue: exact d, packed key, min over jj then over jg lanes
        #pragma unroll
        for (int rr = 0; rr < 4; ++rr) {
            const int n = rows_s[rg * 4 + rr];
            const float An = A[n];
            unsigned long long best = ~0ull;
            #pragma unroll
            for (int jj = 0; jj < 4; ++jj) {
                int j = j0 + jg + 32 * jj;
                float tt = An + ce[j];
                float d = fmaf(-2.0f, acc[rr][jj], tt);   // == R2 epilogue bits
                unsigned int sd = __float_as_uint(d);
                sd = (sd & 0x80000000u) ? ~sd : (sd | 0x80000000u);
                unsigned long long key = ((unsigned long long)sd << 32) | (unsigned)j;
                best = key < best ? key : best;
            }
            #pragma unroll
            for (int off = 16; off > 0; off >>= 1) {      // reduce 32 jg lanes
                unsigned long long o = __shfl_xor(best, off, 64);
                best = o < best ? o : best;
            }
            if (jg == 0) atomicMin(&keys[n], best);
        }
    }
}

// ---------------------------------------------------------------------------
// gather z_q + idx unpack + histogram + fp64 SSE reduction
__global__ __launch_bounds__(256) void k_gather(const float* __restrict__ z,
                                                const float* __restrict__ cb,
                                                const unsigned long long* __restrict__ keys,
                                                float* __restrict__ out,
                                                float* __restrict__ out_idx,
                                                int* __restrict__ counts,
                                                double* __restrict__ sse) {
    int bh = blockIdx.x;                 // b*32 + h
    int b = bh >> 5, h = bh & 31;
    int tid = threadIdx.x;
    __shared__ int sidx[32];
    if (tid < 32) {
        int n = b * 1024 + h * 32 + tid;
        unsigned long long k = keys[n];
        int idx = (int)(k & 0xFFFFFFFFull);
        sidx[tid] = idx;
        out_idx[n] = (float)idx;
        atomicAdd(&counts[idx], 1);
    }
    __syncthreads();
    int w = tid & 31, cy = tid >> 5;
    int jid = sidx[w];
    const float* cbr = cb + (size_t)jid * C_DIM;
    size_t zb = (size_t)b * 262144 + h * 32 + w;

    double acc = 0.0;
    #pragma unroll 4
    for (int cc = 0; cc < 32; ++cc) {
        int c = cc * 8 + cy;
        float e = cbr[c];
        size_t zi = zb + (size_t)c * 1024;
        float d = e - z[zi];
        out[zi] = e;
        acc += (double)(d * d);
    }
    #pragma unroll
    for (int off = 32; off > 0; off >>= 1) acc += __shfl_down(acc, off, 64);
    __shared__ double sh[4];
    if ((tid & 63) == 0) sh[tid >> 6] = acc;
    __syncthreads();
    if (tid == 0) atomicAdd(sse, sh[0] + sh[1] + sh[2] + sh[3]);
}

// ---------------------------------------------------------------------------
// parallel scalar reductions: blocks [0,64) -> S = ||M||_F^2 into accum[1];
// blocks [64,96) -> H = sum p*log(p+1e-10) into accum[2].
__global__ __launch_bounds__(256) void k_msq(const float* __restrict__ M,
                                             const int* __restrict__ counts,
                                             double* __restrict__ accum) {
    const int tid = threadIdx.x, bid = blockIdx.x;
    __shared__ double sh[4];
    double s = 0.0;
    if (bid < 64) {
        const float* p = &M[bid * 1024 + tid * 4];
        float4 v = *(const float4*)p;
        s = (double)v.x * v.x + (double)v.y * v.y
          + (double)v.z * v.z + (double)v.w * v.w;
    } else {
        int j = (bid - 64) * 256 + tid;
        double p = counts[j] * (1.0 / (double)N_VEC);
        s = p * log(p + 1e-10);
    }
    #pragma unroll
    for (int off = 32; off > 0; off >>= 1) s += __shfl_down(s, off, 64);
    if ((tid & 63) == 0) sh[tid >> 6] = s;
    __syncthreads();
    if (tid == 0)
        atomicAdd(&accum[bid < 64 ? 1 : 2], sh[0] + sh[1] + sh[2] + sh[3]);
}

// ---------------------------------------------------------------------------
// finalize scalars (trivial): loss, ortho, perplexity from accum
__global__ __launch_bounds__(64) void k_final(const double* __restrict__ accum,
                                              float* __restrict__ out_scalars) {
    if (threadIdx.x == 0) {
        out_scalars[0] = (float)(1.25 * accum[0] / (double)N_ELEM);               // loss
        out_scalars[1] = (float)((accum[1] - (double)N_E) / ((double)N_E * N_E)); // ortho
        out_scalars[2] = (float)exp(-accum[2]);                                   // perplexity
    }
}

// ---------------------------------------------------------------------------
extern "C" void kernel_launch(void* const* d_in, const int* in_sizes, int n_in,
                              void* d_out, int out_size, void* d_ws, size_t ws_size,
                              hipStream_t stream) {
    (void)in_sizes; (void)n_in; (void)out_size; (void)ws_size;
    const float* z  = (const float*)d_in[0];
    const float* cb = (const float*)d_in[1];
    float* out = (float*)d_out;

    char* ws = (char*)d_ws;
    int* counts            = (int*)(ws + WS_COUNTS);
    float* M               = (float*)(ws + WS_M);
    double* accum          = (double*)(ws + WS_ACCUM);
    int* listlen           = (int*)(ws + WS_LISTLEN);
    float* ce              = (float*)(ws + WS_CE);
    float* rn              = (float*)(ws + WS_RN);
    float* A               = (float*)(ws + WS_A);
    unsigned long long* keys = (unsigned long long*)(ws + WS_KEYS);
    int* lists             = (int*)(ws + WS_LISTS);
    float* tilemin         = (float*)(ws + WS_TILEMIN);
    unsigned short* zbf    = (unsigned short*)(ws + WS_ZBF);
    unsigned short* cbbf   = (unsigned short*)(ws + WS_CBBF);
    float* thr             = (float*)(ws + WS_THR);
    float* zT              = (float*)(ws + WS_ZT);

    float* out_scalars = out + N_ELEM;       // loss, ortho, perplexity
    float* out_idx     = out + N_ELEM + 3;   // 16384 idx as float

    hipMemsetAsync(ws, 0, WS_ZERO_BYTES, stream);   // counts + M + accum + listlen

    k_cbprep<<<N_E, 256, 0, stream>>>(cb, ce, rn, cbbf);
    k_ztrans<<<N_VEC / 64, 256, 0, stream>>>(z, zbf, zT, A);
    k_mfma<<<8704, 256, 0, stream>>>(zbf, cbbf, cb, rn, tilemin, M);
    k_rowmin<<<N_VEC / 64, 256, 0, stream>>>(tilemin, thr, keys);
    k_build<<<dim3(64, 8), 256, 0, stream>>>(tilemin, thr, listlen, lists);
    k_refine2<<<dim3(64, 128), 256, 0, stream>>>(zT, cb, ce, A, listlen, lists, keys);
    k_gather<<<512, 256, 0, stream>>>(z, cb, keys, out, out_idx, counts, accum);
    k_msq<<<96, 256, 0, stream>>>(M, counts, accum);
    k_final<<<1, 64, 0, stream>>>(accum, out_scalars);
}

// Round 15
// 343.126 us; speedup vs baseline: 1.4246x; 1.0468x over previous
//
#include <hip/hip_runtime.h>
#include <hip/hip_bf16.h>
#include <math.h>

// ---------------------------------------------------------------------------
// VQ quantizer:
//   in[0] = z        (16,256,32,32) fp32   -> N=16384 vectors of C=256
//   in[1] = codebook (8192,256)     fp32
//   out   = [ z_q (B,C,H,W) 4194304 | loss | ortho | perplexity | idx(16384) as float ]
//
// idx strategy (two-stage, bit-matching the R2..R14 passing semantics):
//   Stage A: bf16 MFMA GEMM; tilemin[t][n] = -2*max_j dot_approx (err<=1.54e-4)
//   Stage B: rows whose tilemin is within MARGIN of rowmin get the EXACT fp32
//            chain recomputed tile-centrically; d = fmaf(-2,acc, A_n + ce_j)
//            == R2 bits; packed-key atomicMin, lowest-index tie-break.
//
// R15 = R14 with the gram fusion REVERTED (R14 lesson: fused dispatch ran
// 168us vs 108.5 standalone -- co-compiled regalloc 68->108 VGPR tanked
// occupancy, and tail-dispatched gram blocks gave zero overlap).  k_mfma and
// k_gram are R12-verbatim standalone.  k_rowmin+k_build merged into k_cand2
// (block already holds the 64x64 tilemin slab; saves a launch + 4MB pass).
// k_msq/k_final split kept (R14's real win).
// ---------------------------------------------------------------------------

#define N_E     8192
#define C_DIM   256
#define N_VEC   16384            // 16*32*32
#define N_ELEM  4194304          // 16*256*32*32
#define MARGIN  6.0e-4f

// ws layout (bytes) -- zero-init fields packed first (single memset)
#define WS_COUNTS   0            // int[8192]                 32768
#define WS_M        32768        // float[65536]              262144
#define WS_ACCUM    294912       // double[4] {sse,S,H,-}     32
#define WS_LISTLEN  294944       // int[64]                   256
#define WS_ZERO_BYTES 295200
#define WS_CE       295200       // float[8192]               32768
#define WS_RN       327968       // float[8192]               32768
#define WS_A        360736       // float[16384]              65536
#define WS_KEYS     426272       // u64[16384]                131072
#define WS_LISTS    557344       // int[64*16384]             4194304
#define WS_TILEMIN  4751648      // float[64*16384] [t][n]    4194304
#define WS_ZBF      8945952      // ushort[16384*256]         8388608
#define WS_CBBF     17334560     // ushort[8192*256]          4194304
#define WS_ZT       21528864     // float[16384*256]          16777216

typedef short short8v __attribute__((ext_vector_type(8)));
typedef float f32x4  __attribute__((ext_vector_type(4)));

__device__ inline unsigned short f2bf(float f) {       // RNE fp32->bf16 (no NaN in data)
    unsigned int x = __float_as_uint(f);
    return (unsigned short)((x + 0x7fffu + ((x >> 16) & 1u)) >> 16);
}

// async 16B/lane global->LDS DMA (gfx950).  LDS dest = wave-uniform base +
// lane*16; global src is per-lane.
__device__ inline void gload16(const void* g, void* l) {
    __builtin_amdgcn_global_load_lds(
        (const __attribute__((address_space(1))) unsigned int*)g,
        (__attribute__((address_space(3))) unsigned int*)l, 16, 0, 0);
}

// ---------------------------------------------------------------------------
// codebook prep: row sqnorm ce (bits == R2..R14), recip norm rn, bf16 cast
__global__ __launch_bounds__(256) void k_cbprep(const float* __restrict__ cb,
                                                float* __restrict__ ce,
                                                float* __restrict__ rn,
                                                unsigned short* __restrict__ cbbf) {
    int j = blockIdx.x;
    int tid = threadIdx.x;
    float v = cb[(size_t)j * C_DIM + tid];
    cbbf[(size_t)j * C_DIM + tid] = f2bf(v);
    float s = v * v;
    #pragma unroll
    for (int off = 32; off > 0; off >>= 1) s += __shfl_down(s, off, 64);
    __shared__ float sh[4];
    if ((tid & 63) == 0) sh[tid >> 6] = s;
    __syncthreads();
    if (tid == 0) {
        float t = sh[0] + sh[1] + sh[2] + sh[3];
        ce[j] = t;
        rn[j] = 1.0f / sqrtf(t);
    }
}

// ---------------------------------------------------------------------------
// z prep: LDS-staged transpose -> zbf (bf16) + zT (fp32), both with coalesced
// 16B/lane writes; A[n] computed from the LDS tile with the R2-VERBATIM
// k-ascending fmaf chain (same values, same order -> identical bits).
__global__ __launch_bounds__(256) void k_ztrans(const float* __restrict__ z,
                                                unsigned short* __restrict__ zbf,
                                                float* __restrict__ zT,
                                                float* __restrict__ A) {
    __shared__ float tile[64 * 260];             // [hw][c], stride 260
    const int tid = threadIdx.x;
    const int n0 = blockIdx.x * 64;
    const int b = n0 >> 10, hw0 = n0 & 1023;
    const float* zp = z + (size_t)b * 262144 + hw0;

    const int hw = tid & 63, cg = tid >> 6;      // 4 c per pass, coalesced over hw
    #pragma unroll 8
    for (int p = 0; p < 64; ++p) {
        int c = p * 4 + cg;
        tile[hw * 260 + c] = zp[(size_t)c * 1024 + hw];
    }
    __syncthreads();

    if (tid < 64) {                              // A[n]: R2-verbatim chain
        float a = 0.0f;
        #pragma unroll 8
        for (int c = 0; c < C_DIM; ++c) {
            float v = tile[tid * 260 + c];
            a = fmaf(v, v, a);
        }
        A[n0 + tid] = a;
    }

    const int r = tid >> 2, q = tid & 3;         // row, 64-c quarter
    unsigned short* dst = zbf + (size_t)(n0 + r) * C_DIM + q * 64;
    float* dstT         = zT  + (size_t)(n0 + r) * C_DIM + q * 64;
    const float* src = &tile[r * 260 + q * 64];
    #pragma unroll
    for (int i = 0; i < 8; ++i) {
        f32x4 lo = *(const f32x4*)&src[i * 8];
        f32x4 hi = *(const f32x4*)&src[i * 8 + 4];
        *(f32x4*)&dstT[i * 8]     = lo;
        *(f32x4*)&dstT[i * 8 + 4] = hi;
        short8v u;
        #pragma unroll
        for (int x = 0; x < 4; ++x) { u[x] = (short)f2bf(lo[x]); u[4 + x] = (short)f2bf(hi[x]); }
        *(short8v*)(dst + i * 8) = u;            // 16B/lane, rows contiguous
    }
}

// ---------------------------------------------------------------------------
// Stage A (R12-verbatim standalone): bf16 MFMA GEMM, 128n x 128j per block
// (4 waves, 2x2), K=256, 2-level XCD swizzle.  gload_lds DMA into LINEAR
// tiles; XOR slot swizzle on BOTH global source and LDS read (conflict-free).
// MFMA kc/kk/acc order verbatim -> tilemin bits unchanged.
__global__ __launch_bounds__(256) void k_mfma(const unsigned short* __restrict__ zbf,
                                              const unsigned short* __restrict__ cbbf,
                                              float* __restrict__ tilemin) {
    __shared__ unsigned short As[128 * 64];   // [n][k] linear (DMA dest)
    __shared__ unsigned short Bs[128 * 64];   // [j][k] linear
    __shared__ float smin[128][2];

    const int tid = threadIdx.x;
    const int lin = blockIdx.x;
    const int x = lin & 7, r = lin >> 3;                  // XCD, rank within
    const int jp = r >> 7, q = r & 127;
    const int by = x * 16 + (q >> 3), bx = jp * 8 + (q & 7);
    const int n0 = by * 128, j0 = bx * 128;
    const int wave = tid >> 6, lane = tid & 63;
    const int wx = wave & 1, wy = wave >> 1;              // wave tile: 64n x 64j
    const int g = lane >> 4, c = lane & 15;

    const int lrow  = lane >> 3;
    const int lslot = (lane & 7) ^ lrow;
    const int rbase = wave * 32;                          // wave-uniform

    f32x4 acc[4][4];
    #pragma unroll
    for (int i = 0; i < 4; ++i)
        #pragma unroll
        for (int j = 0; j < 4; ++j) acc[i][j] = (f32x4){0.f, 0.f, 0.f, 0.f};

    for (int kc = 0; kc < C_DIM; kc += 64) {
        __syncthreads();                                  // prev reads done
        #pragma unroll
        for (int i = 0; i < 4; ++i) {
            const int row8 = rbase + i * 8;
            const unsigned short* ga =
                zbf  + (size_t)(n0 + row8 + lrow) * C_DIM + kc + lslot * 8;
            const unsigned short* gb =
                cbbf + (size_t)(j0 + row8 + lrow) * C_DIM + kc + lslot * 8;
            gload16(ga, &As[row8 * 64]);
            gload16(gb, &Bs[row8 * 64]);
        }
        __syncthreads();                                  // vmcnt(0): tiles resident

        #pragma unroll
        for (int kk = 0; kk < 2; ++kk) {
            short8v a[4], b[4];
            #pragma unroll
            for (int f = 0; f < 4; ++f) {
                const int row = wy * 64 + f * 16 + c;
                a[f] = *(const short8v*)&As[row * 64 + (((kk * 4 + g) ^ (c & 7)) * 8)];
            }
            #pragma unroll
            for (int f = 0; f < 4; ++f) {
                const int row = wx * 64 + f * 16 + c;
                b[f] = *(const short8v*)&Bs[row * 64 + (((kk * 4 + g) ^ (c & 7)) * 8)];
            }
            #pragma unroll
            for (int nf = 0; nf < 4; ++nf)
                #pragma unroll
                for (int jf = 0; jf < 4; ++jf)
                    acc[nf][jf] = __builtin_amdgcn_mfma_f32_16x16x32_bf16(
                        a[nf], b[jf], acc[nf][jf], 0, 0, 0);
        }
    }

    // C layout: col(j) = lane&15, row(n) = (lane>>4)*4 + reg.  max over j.
    #pragma unroll
    for (int nf = 0; nf < 4; ++nf) {
        #pragma unroll
        for (int rr = 0; rr < 4; ++rr) {
            float mx = acc[nf][0][rr];
            #pragma unroll
            for (int jf = 1; jf < 4; ++jf) mx = fmaxf(mx, acc[nf][jf][rr]);
            #pragma unroll
            for (int off = 1; off < 16; off <<= 1)
                mx = fmaxf(mx, __shfl_xor(mx, off, 64));
            if (c == 0) smin[wy * 64 + nf * 16 + g * 4 + rr][wx] = -2.0f * mx;
        }
    }
    __syncthreads();
    if (tid < 128)
        tilemin[(size_t)bx * N_VEC + n0 + tid] = fminf(smin[tid][0], smin[tid][1]);
}

// ---------------------------------------------------------------------------
// Stage B1 (merged rowmin+build): per 64-n slab, compute thr[n] (min over all
// 64 tiles + MARGIN), re-arm keys, then ballot-compact每 tile's qualifying n
// into its list.  Wave = 64 consecutive n (same coalescing as old k_build).
// List order differs from R14 -- keyed atomicMin downstream is order-blind.
__global__ __launch_bounds__(256) void k_cand2(const float* __restrict__ tilemin,
                                               unsigned long long* __restrict__ keys,
                                               int* __restrict__ listlen,
                                               int* __restrict__ lists) {
    __shared__ float red[4][64];
    __shared__ float thr_s[64];
    const int nl = threadIdx.x & 63, tg = threadIdx.x >> 6;
    const int n = blockIdx.x * 64 + nl;

    float m = 3.4e38f;
    #pragma unroll
    for (int i = 0; i < 16; ++i)
        m = fminf(m, tilemin[(size_t)(tg * 16 + i) * N_VEC + n]);
    red[tg][nl] = m;
    __syncthreads();
    if (tg == 0) {
        thr_s[nl] = fminf(fminf(red[0][nl], red[1][nl]),
                          fminf(red[2][nl], red[3][nl])) + MARGIN;
        keys[n] = ~0ull;
    }
    __syncthreads();
    const float thr = thr_s[nl];

    #pragma unroll
    for (int i = 0; i < 16; ++i) {
        const int t = tg * 16 + i;
        bool qq = tilemin[(size_t)t * N_VEC + n] <= thr;   // L2-hot re-read
        unsigned long long mask = __ballot(qq);
        if (mask) {
            int ldr = __ffsll(mask) - 1;
            int base = 0;
            if (nl == ldr) base = atomicAdd(&listlen[t], __popcll(mask));
            base = __shfl(base, ldr, 64);
            if (qq) {
                int pre = __popcll(mask & ((1ull << nl) - 1ull));
                lists[t * N_VEC + base + pre] = n;
            }
        }
    }
}

// ---------------------------------------------------------------------------
// Stage B2: tile-centric exact refine (R12-verbatim).  grid (64, 128).
__global__ __launch_bounds__(256) void k_refine2(const float* __restrict__ zT,
                                                 const float* __restrict__ cb,
                                                 const float* __restrict__ ce,
                                                 const float* __restrict__ A,
                                                 const int* __restrict__ listlen,
                                                 const int* __restrict__ lists,
                                                 unsigned long long* __restrict__ keys) {
    __shared__ float e_s[128 * 68];
    __shared__ float z_s[32 * 68];
    __shared__ int   rows_s[32];

    const int t = blockIdx.x;
    const int len = listlen[t];
    const int tid = threadIdx.x;
    const int jg = tid & 31, rg = tid >> 5;
    const int j0 = t * 128;

    for (int b0 = blockIdx.y * 32; b0 < len; b0 += 128 * 32) {
        const int nrows = min(32, len - b0);
        __syncthreads();                           // protect prev batch's LDS
        if (tid < 32)
            rows_s[tid] = lists[t * N_VEC + b0 + min(tid, nrows - 1)];  // pad dup row0

        float acc[4][4];
        #pragma unroll
        for (int rr = 0; rr < 4; ++rr)
            #pragma unroll
            for (int jj = 0; jj < 4; ++jj) acc[rr][jj] = 0.0f;

        for (int kc = 0; kc < C_DIM; kc += 64) {
            __syncthreads();
            {   // stage e chunk: 128 j x 64 k
                int jr = tid >> 1, ko = (tid & 1) * 32;
                #pragma unroll
                for (int i = 0; i < 8; ++i)
                    *(float4*)&e_s[jr * 68 + ko + i * 4] =
                        *(const float4*)&cb[(size_t)(j0 + jr) * C_DIM + kc + ko + i * 4];
            }
            {   // stage z chunk: 32 rows x 64 k from zT (R5-verbatim, coalesced)
                int r = tid >> 3, ko = (tid & 7) * 8;
                const float* zp = &zT[(size_t)rows_s[r] * C_DIM + kc + ko];
                *(float4*)&z_s[r * 68 + ko]     = *(const float4*)&zp[0];
                *(float4*)&z_s[r * 68 + ko + 4] = *(const float4*)&zp[4];
            }
            __syncthreads();

            #pragma unroll
            for (int k4 = 0; k4 < 16; ++k4) {
                float4 ef[4], zf[4];
                #pragma unroll
                for (int jj = 0; jj < 4; ++jj)
                    ef[jj] = *(const float4*)&e_s[(jg + 32 * jj) * 68 + k4 * 4];
                #pragma unroll
                for (int rr = 0; rr < 4; ++rr)
                    zf[rr] = *(const float4*)&z_s[(rg * 4 + rr) * 68 + k4 * 4];
                #pragma unroll
                for (int kk = 0; kk < 4; ++kk)       // k ascending: exact chain
                    #pragma unroll
                    for (int rr = 0; rr < 4; ++rr)
                        #pragma unroll
                        for (int jj = 0; jj < 4; ++jj)
                            acc[rr][jj] = fmaf(((const float*)&zf[rr])[kk],
                                               ((const float*)&ef[jj])[kk], acc[rr][jj]);
            }
        }

        // epilogue: exact d, packed key, min over jj then over jg lanes
        #pragma unroll
        for (int rr = 0; rr < 4; ++rr) {
            const int n = rows_s[rg * 4 + rr];
            const float An = A[n];
            unsigned long long best = ~0ull;
            #pragma unroll
            for (int jj = 0; jj < 4; ++jj) {
                int j = j0 + jg + 32 * jj;
                float tt = An + ce[j];
                float d = fmaf(-2.0f, acc[rr][jj], tt);   // == R2 epilogue bits
                unsigned int sd = __float_as_uint(d);
                sd = (sd & 0x80000000u) ? ~sd : (sd | 0x80000000u);
                unsigned long long key = ((unsigned long long)sd << 32) | (unsigned)j;
                best = key < best ? key : best;
            }
            #pragma unroll
            for (int off = 16; off > 0; off >>= 1) {      // reduce 32 jg lanes
                unsigned long long o = __shfl_xor(best, off, 64);
                best = o < best ? o : best;
            }
            if (jg == 0) atomicMin(&keys[n], best);
        }
    }
}

// ---------------------------------------------------------------------------
// gather z_q + idx unpack + histogram + fp64 SSE reduction
__global__ __launch_bounds__(256) void k_gather(const float* __restrict__ z,
                                                const float* __restrict__ cb,
                                                const unsigned long long* __restrict__ keys,
                                                float* __restrict__ out,
                                                float* __restrict__ out_idx,
                                                int* __restrict__ counts,
                                                double* __restrict__ sse) {
    int bh = blockIdx.x;                 // b*32 + h
    int b = bh >> 5, h = bh & 31;
    int tid = threadIdx.x;
    __shared__ int sidx[32];
    if (tid < 32) {
        int n = b * 1024 + h * 32 + tid;
        unsigned long long k = keys[n];
        int idx = (int)(k & 0xFFFFFFFFull);
        sidx[tid] = idx;
        out_idx[n] = (float)idx;
        atomicAdd(&counts[idx], 1);
    }
    __syncthreads();
    int w = tid & 31, cy = tid >> 5;
    int jid = sidx[w];
    const float* cbr = cb + (size_t)jid * C_DIM;
    size_t zb = (size_t)b * 262144 + h * 32 + w;

    double acc = 0.0;
    #pragma unroll 4
    for (int cc = 0; cc < 32; ++cc) {
        int c = cc * 8 + cy;
        float e = cbr[c];
        size_t zi = zb + (size_t)c * 1024;
        float d = e - z[zi];
        out[zi] = e;
        acc += (double)(d * d);
    }
    #pragma unroll
    for (int off = 32; off > 0; off >>= 1) acc += __shfl_down(acc, off, 64);
    __shared__ double sh[4];
    if ((tid & 63) == 0) sh[tid >> 6] = acc;
    __syncthreads();
    if (tid == 0) atomicAdd(sse, sh[0] + sh[1] + sh[2] + sh[3]);
}

// ---------------------------------------------------------------------------
// Gram matrix M = Wn^T Wn  (256x256), j-split with float atomics (R12-verbatim)
__global__ __launch_bounds__(256) void k_gram(const float* __restrict__ cb,
                                              const float* __restrict__ rn,
                                              float* __restrict__ M) {
    __shared__ float aT[64][68];
    __shared__ float bT[64][68];
    int k0 = blockIdx.x * 64, l0 = blockIdx.y * 64;
    int jc0 = blockIdx.z * 256;
    int tid = threadIdx.x;
    int tk = tid & 15, tl = tid >> 4;
    float acc[4][4];
    #pragma unroll
    for (int i = 0; i < 4; ++i)
        #pragma unroll
        for (int l = 0; l < 4; ++l) acc[i][l] = 0.0f;

    for (int jc = jc0; jc < jc0 + 256; jc += 64) {
        __syncthreads();
        {
            int kk = tid & 63, jj0 = tid >> 6;
            #pragma unroll
            for (int p = 0; p < 16; ++p) {
                int jj = p * 4 + jj0;
                float r = rn[jc + jj];
                const float* row = cb + (size_t)(jc + jj) * C_DIM;
                aT[jj][kk] = row[k0 + kk] * r;
                bT[jj][kk] = row[l0 + kk] * r;
            }
        }
        __syncthreads();
        #pragma unroll 8
        for (int jj = 0; jj < 64; ++jj) {
            float4 av = *(const float4*)&aT[jj][tk * 4];
            float4 bv = *(const float4*)&bT[jj][tl * 4];
            float a4[4] = {av.x, av.y, av.z, av.w};
            float b4[4] = {bv.x, bv.y, bv.z, bv.w};
            #pragma unroll
            for (int i = 0; i < 4; ++i)
                #pragma unroll
                for (int l = 0; l < 4; ++l)
                    acc[i][l] = fmaf(a4[i], b4[l], acc[i][l]);
        }
    }
    #pragma unroll
    for (int i = 0; i < 4; ++i)
        #pragma unroll
        for (int l = 0; l < 4; ++l)
            atomicAdd(&M[(size_t)(k0 + tk * 4 + i) * C_DIM + l0 + tl * 4 + l], acc[i][l]);
}

// ---------------------------------------------------------------------------
// parallel scalar reductions: blocks [0,64) -> S = ||M||_F^2 into accum[1];
// blocks [64,96) -> H = sum p*log(p+1e-10) into accum[2].
__global__ __launch_bounds__(256) void k_msq(const float* __restrict__ M,
                                             const int* __restrict__ counts,
                                             double* __restrict__ accum) {
    const int tid = threadIdx.x, bid = blockIdx.x;
    __shared__ double sh[4];
    double s = 0.0;
    if (bid < 64) {
        const float* p = &M[bid * 1024 + tid * 4];
        float4 v = *(const float4*)p;
        s = (double)v.x * v.x + (double)v.y * v.y
          + (double)v.z * v.z + (double)v.w * v.w;
    } else {
        int j = (bid - 64) * 256 + tid;
        double p = counts[j] * (1.0 / (double)N_VEC);
        s = p * log(p + 1e-10);
    }
    #pragma unroll
    for (int off = 32; off > 0; off >>= 1) s += __shfl_down(s, off, 64);
    if ((tid & 63) == 0) sh[tid >> 6] = s;
    __syncthreads();
    if (tid == 0)
        atomicAdd(&accum[bid < 64 ? 1 : 2], sh[0] + sh[1] + sh[2] + sh[3]);
}

// ---------------------------------------------------------------------------
// finalize scalars (trivial): loss, ortho, perplexity from accum
__global__ __launch_bounds__(64) void k_final(const double* __restrict__ accum,
                                              float* __restrict__ out_scalars) {
    if (threadIdx.x == 0) {
        out_scalars[0] = (float)(1.25 * accum[0] / (double)N_ELEM);               // loss
        out_scalars[1] = (float)((accum[1] - (double)N_E) / ((double)N_E * N_E)); // ortho
        out_scalars[2] = (float)exp(-accum[2]);                                   // perplexity
    }
}

// ---------------------------------------------------------------------------
extern "C" void kernel_launch(void* const* d_in, const int* in_sizes, int n_in,
                              void* d_out, int out_size, void* d_ws, size_t ws_size,
                              hipStream_t stream) {
    (void)in_sizes; (void)n_in; (void)out_size; (void)ws_size;
    const float* z  = (const float*)d_in[0];
    const float* cb = (const float*)d_in[1];
    float* out = (float*)d_out;

    char* ws = (char*)d_ws;
    int* counts            = (int*)(ws + WS_COUNTS);
    float* M               = (float*)(ws + WS_M);
    double* accum          = (double*)(ws + WS_ACCUM);
    int* listlen           = (int*)(ws + WS_LISTLEN);
    float* ce              = (float*)(ws + WS_CE);
    float* rn              = (float*)(ws + WS_RN);
    float* A               = (float*)(ws + WS_A);
    unsigned long long* keys = (unsigned long long*)(ws + WS_KEYS);
    int* lists             = (int*)(ws + WS_LISTS);
    float* tilemin         = (float*)(ws + WS_TILEMIN);
    unsigned short* zbf    = (unsigned short*)(ws + WS_ZBF);
    unsigned short* cbbf   = (unsigned short*)(ws + WS_CBBF);
    float* zT              = (float*)(ws + WS_ZT);

    float* out_scalars = out + N_ELEM;       // loss, ortho, perplexity
    float* out_idx     = out + N_ELEM + 3;   // 16384 idx as float

    hipMemsetAsync(ws, 0, WS_ZERO_BYTES, stream);   // counts + M + accum + listlen

    k_cbprep<<<N_E, 256, 0, stream>>>(cb, ce, rn, cbbf);
    k_ztrans<<<N_VEC / 64, 256, 0, stream>>>(z, zbf, zT, A);
    k_mfma<<<8192, 256, 0, stream>>>(zbf, cbbf, tilemin);
    k_cand2<<<N_VEC / 64, 256, 0, stream>>>(tilemin, keys, listlen, lists);
    k_refine2<<<dim3(64, 128), 256, 0, stream>>>(zT, cb, ce, A, listlen, lists, keys);
    k_gather<<<512, 256, 0, stream>>>(z, cb, keys, out, out_idx, counts, accum);
    k_gram<<<dim3(4, 4, 32), 256, 0, stream>>>(cb, rn, M);
    k_msq<<<96, 256, 0, stream>>>(M, counts, accum);
    k_final<<<1, 64, 0, stream>>>(accum, out_scalars);
}

// Round 17
// 341.844 us; speedup vs baseline: 1.4299x; 1.0038x over previous
//
#include <hip/hip_runtime.h>
#include <hip/hip_bf16.h>
#include <math.h>

// ---------------------------------------------------------------------------
// VQ quantizer:
//   in[0] = z        (16,256,32,32) fp32   -> N=16384 vectors of C=256
//   in[1] = codebook (8192,256)     fp32
//   out   = [ z_q (B,C,H,W) 4194304 | loss | ortho | perplexity | idx(16384) as float ]
//
// idx strategy (two-stage, bit-matching the R2..R15 passing semantics):
//   Stage A: bf16 MFMA GEMM; tilemin[t][n] = -2*max_j dot_approx (err<=1.54e-4)
//   Stage B: rows whose tilemin is within MARGIN of rowmin get the EXACT fp32
//            chain recomputed tile-centrically; d = fmaf(-2,acc, A_n + ce_j)
//            == R2 bits; packed-key atomicMin, lowest-index tie-break.
//
// R17 = R16 with the done-counter finalize REMOVED (R16 post-timing NaN:
// intra-kernel cross-block sync on non-coherent XCDs -- G16).  Same 6 nodes,
// but all ordering is graph-node-boundary only:
//   node 5 (k_gather): +64 blocks reducing ||M||_F^2 -> atomicAdd accum[1]
//   node 6 (k_final):  ONE block does the whole 8192-count entropy (32
//                      logs/thread) + reads accum[0..1] plainly + writes the
//                      3 scalars.  No cross-block dependence anywhere.
// ---------------------------------------------------------------------------

#define N_E     8192
#define C_DIM   256
#define N_VEC   16384            // 16*32*32
#define N_ELEM  4194304          // 16*256*32*32
#define MARGIN  6.0e-4f

// ws layout (bytes)
#define WS_COUNTS   0            // int[8192]                 32768
#define WS_M        32768        // float[65536]              262144
#define WS_ACCUM    294912       // double[4] {sse,S,-,-}     32
#define WS_LISTLEN  294944       // int[64]                   256
#define WS_CE       295200       // float[8192]               32768
#define WS_RN       327968       // float[8192]               32768
#define WS_A        360736       // float[16384]              65536
#define WS_KEYS     426272       // u64[16384]                131072
#define WS_LISTS    557344       // int[64*16384]             4194304
#define WS_TILEMIN  4751648      // float[64*16384] [t][n]    4194304
#define WS_ZBF      8945952      // ushort[16384*256]         8388608
#define WS_CBBF     17334560     // ushort[8192*256]          4194304
#define WS_ZT       21528864     // float[16384*256]          16777216

typedef short short8v __attribute__((ext_vector_type(8)));
typedef float f32x4  __attribute__((ext_vector_type(4)));

__device__ inline unsigned short f2bf(float f) {       // RNE fp32->bf16 (no NaN in data)
    unsigned int x = __float_as_uint(f);
    return (unsigned short)((x + 0x7fffu + ((x >> 16) & 1u)) >> 16);
}

// async 16B/lane global->LDS DMA (gfx950).  LDS dest = wave-uniform base +
// lane*16; global src is per-lane.
__device__ inline void gload16(const void* g, void* l) {
    __builtin_amdgcn_global_load_lds(
        (const __attribute__((address_space(1))) unsigned int*)g,
        (__attribute__((address_space(3))) unsigned int*)l, 16, 0, 0);
}

// ---------------------------------------------------------------------------
// prep: blocks [0,8192) = cbprep verbatim (+ ws zero-init relocations);
//       blocks [8192,8448) = ztrans verbatim (+ M zero-init).
__global__ __launch_bounds__(256) void k_prep(const float* __restrict__ cb,
                                              const float* __restrict__ z,
                                              float* __restrict__ ce,
                                              float* __restrict__ rn,
                                              unsigned short* __restrict__ cbbf,
                                              unsigned short* __restrict__ zbf,
                                              float* __restrict__ zT,
                                              float* __restrict__ A,
                                              float* __restrict__ M,
                                              int* __restrict__ counts,
                                              int* __restrict__ listlen,
                                              double* __restrict__ accum) {
    __shared__ float tile[64 * 260];             // ztrans buffer; cbprep uses 16B slice
    const int tid = threadIdx.x;

    if (blockIdx.x < 8192) {
        // ---- cbprep path (verbatim; sh[4] -> tile slice) ----
        const int j = blockIdx.x;
        if (tid == 0) {
            counts[j] = 0;
            if (j < 64) listlen[j] = 0;
            if (j == 0) {
                accum[0] = 0.0; accum[1] = 0.0; accum[2] = 0.0; accum[3] = 0.0;
            }
        }
        float v = cb[(size_t)j * C_DIM + tid];
        cbbf[(size_t)j * C_DIM + tid] = f2bf(v);
        float s = v * v;
        #pragma unroll
        for (int off = 32; off > 0; off >>= 1) s += __shfl_down(s, off, 64);
        if ((tid & 63) == 0) tile[tid >> 6] = s;
        __syncthreads();
        if (tid == 0) {
            float t = tile[0] + tile[1] + tile[2] + tile[3];
            ce[j] = t;
            rn[j] = 1.0f / sqrtf(t);
        }
    } else {
        // ---- ztrans path (verbatim) + M zero-init ----
        const int bz = blockIdx.x - 8192;        // 0..255
        M[bz * 256 + tid] = 0.0f;                // 256x256 = 65536 floats

        const int n0 = bz * 64;
        const int b = n0 >> 10, hw0 = n0 & 1023;
        const float* zp = z + (size_t)b * 262144 + hw0;

        const int hw = tid & 63, cg = tid >> 6;  // 4 c per pass, coalesced over hw
        #pragma unroll 8
        for (int p = 0; p < 64; ++p) {
            int c = p * 4 + cg;
            tile[hw * 260 + c] = zp[(size_t)c * 1024 + hw];
        }
        __syncthreads();

        if (tid < 64) {                          // A[n]: R2-verbatim chain
            float a = 0.0f;
            #pragma unroll 8
            for (int c = 0; c < C_DIM; ++c) {
                float v = tile[tid * 260 + c];
                a = fmaf(v, v, a);
            }
            A[n0 + tid] = a;
        }

        const int r = tid >> 2, q = tid & 3;     // row, 64-c quarter
        unsigned short* dst = zbf + (size_t)(n0 + r) * C_DIM + q * 64;
        float* dstT         = zT  + (size_t)(n0 + r) * C_DIM + q * 64;
        const float* src = &tile[r * 260 + q * 64];
        #pragma unroll
        for (int i = 0; i < 8; ++i) {
            f32x4 lo = *(const f32x4*)&src[i * 8];
            f32x4 hi = *(const f32x4*)&src[i * 8 + 4];
            *(f32x4*)&dstT[i * 8]     = lo;
            *(f32x4*)&dstT[i * 8 + 4] = hi;
            short8v u;
            #pragma unroll
            for (int x = 0; x < 4; ++x) { u[x] = (short)f2bf(lo[x]); u[4 + x] = (short)f2bf(hi[x]); }
            *(short8v*)(dst + i * 8) = u;        // 16B/lane, rows contiguous
        }
    }
}

// ---------------------------------------------------------------------------
// Stage A (R12/R15-verbatim): bf16 MFMA GEMM, 128n x 128j per block
// (4 waves, 2x2), K=256, 2-level XCD swizzle.  gload_lds DMA into LINEAR
// tiles; XOR slot swizzle on BOTH global source and LDS read (conflict-free).
// MFMA kc/kk/acc order verbatim -> tilemin bits unchanged.
__global__ __launch_bounds__(256) void k_mfma(const unsigned short* __restrict__ zbf,
                                              const unsigned short* __restrict__ cbbf,
                                              float* __restrict__ tilemin) {
    __shared__ unsigned short As[128 * 64];   // [n][k] linear (DMA dest)
    __shared__ unsigned short Bs[128 * 64];   // [j][k] linear
    __shared__ float smin[128][2];

    const int tid = threadIdx.x;
    const int lin = blockIdx.x;
    const int x = lin & 7, r = lin >> 3;                  // XCD, rank within
    const int jp = r >> 7, q = r & 127;
    const int by = x * 16 + (q >> 3), bx = jp * 8 + (q & 7);
    const int n0 = by * 128, j0 = bx * 128;
    const int wave = tid >> 6, lane = tid & 63;
    const int wx = wave & 1, wy = wave >> 1;              // wave tile: 64n x 64j
    const int g = lane >> 4, c = lane & 15;

    const int lrow  = lane >> 3;
    const int lslot = (lane & 7) ^ lrow;
    const int rbase = wave * 32;                          // wave-uniform

    f32x4 acc[4][4];
    #pragma unroll
    for (int i = 0; i < 4; ++i)
        #pragma unroll
        for (int j = 0; j < 4; ++j) acc[i][j] = (f32x4){0.f, 0.f, 0.f, 0.f};

    for (int kc = 0; kc < C_DIM; kc += 64) {
        __syncthreads();                                  // prev reads done
        #pragma unroll
        for (int i = 0; i < 4; ++i) {
            const int row8 = rbase + i * 8;
            const unsigned short* ga =
                zbf  + (size_t)(n0 + row8 + lrow) * C_DIM + kc + lslot * 8;
            const unsigned short* gb =
                cbbf + (size_t)(j0 + row8 + lrow) * C_DIM + kc + lslot * 8;
            gload16(ga, &As[row8 * 64]);
            gload16(gb, &Bs[row8 * 64]);
        }
        __syncthreads();                                  // vmcnt(0): tiles resident

        #pragma unroll
        for (int kk = 0; kk < 2; ++kk) {
            short8v a[4], b[4];
            #pragma unroll
            for (int f = 0; f < 4; ++f) {
                const int row = wy * 64 + f * 16 + c;
                a[f] = *(const short8v*)&As[row * 64 + (((kk * 4 + g) ^ (c & 7)) * 8)];
            }
            #pragma unroll
            for (int f = 0; f < 4; ++f) {
                const int row = wx * 64 + f * 16 + c;
                b[f] = *(const short8v*)&Bs[row * 64 + (((kk * 4 + g) ^ (c & 7)) * 8)];
            }
            #pragma unroll
            for (int nf = 0; nf < 4; ++nf)
                #pragma unroll
                for (int jf = 0; jf < 4; ++jf)
                    acc[nf][jf] = __builtin_amdgcn_mfma_f32_16x16x32_bf16(
                        a[nf], b[jf], acc[nf][jf], 0, 0, 0);
        }
    }

    // C layout: col(j) = lane&15, row(n) = (lane>>4)*4 + reg.  max over j.
    #pragma unroll
    for (int nf = 0; nf < 4; ++nf) {
        #pragma unroll
        for (int rr = 0; rr < 4; ++rr) {
            float mx = acc[nf][0][rr];
            #pragma unroll
            for (int jf = 1; jf < 4; ++jf) mx = fmaxf(mx, acc[nf][jf][rr]);
            #pragma unroll
            for (int off = 1; off < 16; off <<= 1)
                mx = fmaxf(mx, __shfl_xor(mx, off, 64));
            if (c == 0) smin[wy * 64 + nf * 16 + g * 4 + rr][wx] = -2.0f * mx;
        }
    }
    __syncthreads();
    if (tid < 128)
        tilemin[(size_t)bx * N_VEC + n0 + tid] = fminf(smin[tid][0], smin[tid][1]);
}

// ---------------------------------------------------------------------------
// Stage B1 + Gram, one dispatch (768 blocks):
//   blocks [0,256):   cand2 verbatim -- per 64-n slab: thr = rowmin + MARGIN,
//                     re-arm keys, ballot-compact per-tile candidate lists.
//   blocks [256,768): gram verbatim (M = Wn^T Wn, j-split atomics; M zeroed
//                     in k_prep).  List order arbitrary -- keyed atomicMin
//                     downstream is order-blind.
__global__ __launch_bounds__(256) void k_candgram(const float* __restrict__ tilemin,
                                                  unsigned long long* __restrict__ keys,
                                                  int* __restrict__ listlen,
                                                  int* __restrict__ lists,
                                                  const float* __restrict__ cb,
                                                  const float* __restrict__ rn,
                                                  float* __restrict__ M) {
    __shared__ float buf[2 * 64 * 68];           // gram aT/bT; cand2 uses slices
    const int tid = threadIdx.x;

    if (blockIdx.x < 256) {
        // ---- cand2 path (verbatim; red/thr_s -> buf slices) ----
        float* red   = buf;                      // [4][64]
        float* thr_s = buf + 256;                // [64]
        const int nl = tid & 63, tg = tid >> 6;
        const int n = blockIdx.x * 64 + nl;

        float m = 3.4e38f;
        #pragma unroll
        for (int i = 0; i < 16; ++i)
            m = fminf(m, tilemin[(size_t)(tg * 16 + i) * N_VEC + n]);
        red[tg * 64 + nl] = m;
        __syncthreads();
        if (tg == 0) {
            thr_s[nl] = fminf(fminf(red[0 * 64 + nl], red[1 * 64 + nl]),
                              fminf(red[2 * 64 + nl], red[3 * 64 + nl])) + MARGIN;
            keys[n] = ~0ull;
        }
        __syncthreads();
        const float thr = thr_s[nl];

        #pragma unroll
        for (int i = 0; i < 16; ++i) {
            const int t = tg * 16 + i;
            bool qq = tilemin[(size_t)t * N_VEC + n] <= thr;   // L2-hot re-read
            unsigned long long mask = __ballot(qq);
            if (mask) {
                int ldr = __ffsll(mask) - 1;
                int base = 0;
                if (nl == ldr) base = atomicAdd(&listlen[t], __popcll(mask));
                base = __shfl(base, ldr, 64);
                if (qq) {
                    int pre = __popcll(mask & ((1ull << nl) - 1ull));
                    lists[t * N_VEC + base + pre] = n;
                }
            }
        }
    } else {
        // ---- gram path (verbatim body, linear block mapping) ----
        float* aT = buf;                         // [64][68]
        float* bT = buf + 64 * 68;               // [64][68]
        const int gidx = blockIdx.x - 256;       // 0..511
        const int k0 = (gidx & 3) * 64, l0 = ((gidx >> 2) & 3) * 64;
        const int jc0 = (gidx >> 4) * 256;
        const int tk = tid & 15, tl = tid >> 4;
        float acc[4][4];
        #pragma unroll
        for (int i = 0; i < 4; ++i)
            #pragma unroll
            for (int l = 0; l < 4; ++l) acc[i][l] = 0.0f;

        for (int jc = jc0; jc < jc0 + 256; jc += 64) {
            __syncthreads();
            {
                int kk = tid & 63, jj0 = tid >> 6;
                #pragma unroll
                for (int p = 0; p < 16; ++p) {
                    int jj = p * 4 + jj0;
                    float rr = rn[jc + jj];
                    const float* row = cb + (size_t)(jc + jj) * C_DIM;
                    aT[jj * 68 + kk] = row[k0 + kk] * rr;
                    bT[jj * 68 + kk] = row[l0 + kk] * rr;
                }
            }
            __syncthreads();
            #pragma unroll 8
            for (int jj = 0; jj < 64; ++jj) {
                float4 av = *(const float4*)&aT[jj * 68 + tk * 4];
                float4 bv = *(const float4*)&bT[jj * 68 + tl * 4];
                float a4[4] = {av.x, av.y, av.z, av.w};
                float b4[4] = {bv.x, bv.y, bv.z, bv.w};
                #pragma unroll
                for (int i = 0; i < 4; ++i)
                    #pragma unroll
                    for (int l = 0; l < 4; ++l)
                        acc[i][l] = fmaf(a4[i], b4[l], acc[i][l]);
            }
        }
        #pragma unroll
        for (int i = 0; i < 4; ++i)
            #pragma unroll
            for (int l = 0; l < 4; ++l)
                atomicAdd(&M[(size_t)(k0 + tk * 4 + i) * C_DIM + l0 + tl * 4 + l], acc[i][l]);
    }
}

// ---------------------------------------------------------------------------
// Stage B2: tile-centric exact refine (R12/R15-verbatim).  grid (64, 128).
__global__ __launch_bounds__(256) void k_refine2(const float* __restrict__ zT,
                                                 const float* __restrict__ cb,
                                                 const float* __restrict__ ce,
                                                 const float* __restrict__ A,
                                                 const int* __restrict__ listlen,
                                                 const int* __restrict__ lists,
                                                 unsigned long long* __restrict__ keys) {
    __shared__ float e_s[128 * 68];
    __shared__ float z_s[32 * 68];
    __shared__ int   rows_s[32];

    const int t = blockIdx.x;
    const int len = listlen[t];
    const int tid = threadIdx.x;
    const int jg = tid & 31, rg = tid >> 5;
    const int j0 = t * 128;

    for (int b0 = blockIdx.y * 32; b0 < len; b0 += 128 * 32) {
        const int nrows = min(32, len - b0);
        __syncthreads();                           // protect prev batch's LDS
        if (tid < 32)
            rows_s[tid] = lists[t * N_VEC + b0 + min(tid, nrows - 1)];  // pad dup row0

        float acc[4][4];
        #pragma unroll
        for (int rr = 0; rr < 4; ++rr)
            #pragma unroll
            for (int jj = 0; jj < 4; ++jj) acc[rr][jj] = 0.0f;

        for (int kc = 0; kc < C_DIM; kc += 64) {
            __syncthreads();
            {   // stage e chunk: 128 j x 64 k
                int jr = tid >> 1, ko = (tid & 1) * 32;
                #pragma unroll
                for (int i = 0; i < 8; ++i)
                    *(float4*)&e_s[jr * 68 + ko + i * 4] =
                        *(const float4*)&cb[(size_t)(j0 + jr) * C_DIM + kc + ko + i * 4];
            }
            {   // stage z chunk: 32 rows x 64 k from zT (coalesced)
                int r = tid >> 3, ko = (tid & 7) * 8;
                const float* zp = &zT[(size_t)rows_s[r] * C_DIM + kc + ko];
                *(float4*)&z_s[r * 68 + ko]     = *(const float4*)&zp[0];
                *(float4*)&z_s[r * 68 + ko + 4] = *(const float4*)&zp[4];
            }
            __syncthreads();

            #pragma unroll
            for (int k4 = 0; k4 < 16; ++k4) {
                float4 ef[4], zf[4];
                #pragma unroll
                for (int jj = 0; jj < 4; ++jj)
                    ef[jj] = *(const float4*)&e_s[(jg + 32 * jj) * 68 + k4 * 4];
                #pragma unroll
                for (int rr = 0; rr < 4; ++rr)
                    zf[rr] = *(const float4*)&z_s[(rg * 4 + rr) * 68 + k4 * 4];
                #pragma unroll
                for (int kk = 0; kk < 4; ++kk)       // k ascending: exact chain
                    #pragma unroll
                    for (int rr = 0; rr < 4; ++rr)
                        #pragma unroll
                        for (int jj = 0; jj < 4; ++jj)
                            acc[rr][jj] = fmaf(((const float*)&zf[rr])[kk],
                                               ((const float*)&ef[jj])[kk], acc[rr][jj]);
            }
        }

        // epilogue: exact d, packed key, min over jj then over jg lanes
        #pragma unroll
        for (int rr = 0; rr < 4; ++rr) {
            const int n = rows_s[rg * 4 + rr];
            const float An = A[n];
            unsigned long long best = ~0ull;
            #pragma unroll
            for (int jj = 0; jj < 4; ++jj) {
                int j = j0 + jg + 32 * jj;
                float tt = An + ce[j];
                float d = fmaf(-2.0f, acc[rr][jj], tt);   // == R2 epilogue bits
                unsigned int sd = __float_as_uint(d);
                sd = (sd & 0x80000000u) ? ~sd : (sd | 0x80000000u);
                unsigned long long key = ((unsigned long long)sd << 32) | (unsigned)j;
                best = key < best ? key : best;
            }
            #pragma unroll
            for (int off = 16; off > 0; off >>= 1) {      // reduce 32 jg lanes
                unsigned long long o = __shfl_xor(best, off, 64);
                best = o < best ? o : best;
            }
            if (jg == 0) atomicMin(&keys[n], best);
        }
    }
}

// ---------------------------------------------------------------------------
// node 5: gather z_q + idx unpack + histogram + fp64 SSE (blocks 0..511,
// verbatim) PLUS ||M||_F^2 reduction (blocks 512..575 -> atomicAdd accum[1];
// M is final after node 3).
__global__ __launch_bounds__(256) void k_gather(const float* __restrict__ z,
                                                const float* __restrict__ cb,
                                                const unsigned long long* __restrict__ keys,
                                                const float* __restrict__ M,
                                                float* __restrict__ out,
                                                float* __restrict__ out_idx,
                                                int* __restrict__ counts,
                                                double* __restrict__ accum) {
    const int tid = threadIdx.x;
    __shared__ int sidx[32];
    __shared__ double sh[4];

    if (blockIdx.x >= 512) {
        // ---- S-reduction path: 64 blocks x 1024 M-elements ----
        const int bid = blockIdx.x - 512;
        float4 v = *(const float4*)&M[bid * 1024 + tid * 4];
        double s = (double)v.x * v.x + (double)v.y * v.y
                 + (double)v.z * v.z + (double)v.w * v.w;
        #pragma unroll
        for (int off = 32; off > 0; off >>= 1) s += __shfl_down(s, off, 64);
        if ((tid & 63) == 0) sh[tid >> 6] = s;
        __syncthreads();
        if (tid == 0) atomicAdd(&accum[1], sh[0] + sh[1] + sh[2] + sh[3]);
        return;
    }

    int bh = blockIdx.x;                 // b*32 + h
    int b = bh >> 5, h = bh & 31;
    if (tid < 32) {
        int n = b * 1024 + h * 32 + tid;
        unsigned long long k = keys[n];
        int idx = (int)(k & 0xFFFFFFFFull);
        sidx[tid] = idx;
        out_idx[n] = (float)idx;
        atomicAdd(&counts[idx], 1);
    }
    __syncthreads();
    int w = tid & 31, cy = tid >> 5;
    int jid = sidx[w];
    const float* cbr = cb + (size_t)jid * C_DIM;
    size_t zb = (size_t)b * 262144 + h * 32 + w;

    double acc = 0.0;
    #pragma unroll 4
    for (int cc = 0; cc < 32; ++cc) {
        int c = cc * 8 + cy;
        float e = cbr[c];
        size_t zi = zb + (size_t)c * 1024;
        float d = e - z[zi];
        out[zi] = e;
        acc += (double)(d * d);
    }
    #pragma unroll
    for (int off = 32; off > 0; off >>= 1) acc += __shfl_down(acc, off, 64);
    if ((tid & 63) == 0) sh[tid >> 6] = acc;
    __syncthreads();
    if (tid == 0) atomicAdd(&accum[0], sh[0] + sh[1] + sh[2] + sh[3]);
}

// ---------------------------------------------------------------------------
// node 6: ONE block -- full entropy reduction over counts (32 logs/thread)
// + plain reads of accum[0..1] (node boundary => coherent) + 3 scalars.
__global__ __launch_bounds__(256) void k_final(const int* __restrict__ counts,
                                               const double* __restrict__ accum,
                                               float* __restrict__ out_scalars) {
    const int tid = threadIdx.x;
    __shared__ double sh[4];
    double h = 0.0;
    for (int j = tid; j < N_E; j += 256) {
        double p = counts[j] * (1.0 / (double)N_VEC);
        h += p * log(p + 1e-10);
    }
    #pragma unroll
    for (int off = 32; off > 0; off >>= 1) h += __shfl_down(h, off, 64);
    if ((tid & 63) == 0) sh[tid >> 6] = h;
    __syncthreads();
    if (tid == 0) {
        double H = sh[0] + sh[1] + sh[2] + sh[3];
        out_scalars[0] = (float)(1.25 * accum[0] / (double)N_ELEM);               // loss
        out_scalars[1] = (float)((accum[1] - (double)N_E) / ((double)N_E * N_E)); // ortho
        out_scalars[2] = (float)exp(-H);                                          // perplexity
    }
}

// ---------------------------------------------------------------------------
extern "C" void kernel_launch(void* const* d_in, const int* in_sizes, int n_in,
                              void* d_out, int out_size, void* d_ws, size_t ws_size,
                              hipStream_t stream) {
    (void)in_sizes; (void)n_in; (void)out_size; (void)ws_size;
    const float* z  = (const float*)d_in[0];
    const float* cb = (const float*)d_in[1];
    float* out = (float*)d_out;

    char* ws = (char*)d_ws;
    int* counts            = (int*)(ws + WS_COUNTS);
    float* M               = (float*)(ws + WS_M);
    double* accum          = (double*)(ws + WS_ACCUM);
    int* listlen           = (int*)(ws + WS_LISTLEN);
    float* ce              = (float*)(ws + WS_CE);
    float* rn              = (float*)(ws + WS_RN);
    float* A               = (float*)(ws + WS_A);
    unsigned long long* keys = (unsigned long long*)(ws + WS_KEYS);
    int* lists             = (int*)(ws + WS_LISTS);
    float* tilemin         = (float*)(ws + WS_TILEMIN);
    unsigned short* zbf    = (unsigned short*)(ws + WS_ZBF);
    unsigned short* cbbf   = (unsigned short*)(ws + WS_CBBF);
    float* zT              = (float*)(ws + WS_ZT);

    float* out_scalars = out + N_ELEM;       // loss, ortho, perplexity
    float* out_idx     = out + N_ELEM + 3;   // 16384 idx as float

    k_prep<<<8448, 256, 0, stream>>>(cb, z, ce, rn, cbbf, zbf, zT, A,
                                     M, counts, listlen, accum);
    k_mfma<<<8192, 256, 0, stream>>>(zbf, cbbf, tilemin);
    k_candgram<<<768, 256, 0, stream>>>(tilemin, keys, listlen, lists, cb, rn, M);
    k_refine2<<<dim3(64, 128), 256, 0, stream>>>(zT, cb, ce, A, listlen, lists, keys);
    k_gather<<<576, 256, 0, stream>>>(z, cb, keys, M, out, out_idx, counts, accum);
    k_final<<<1, 256, 0, stream>>>(counts, accum, out_scalars);
}